// Round 10
// baseline (1218.620 us; speedup 1.0000x reference)
//
#include <hip/hip_runtime.h>

#define NN   100000   // nodes
#define EE   1600000  // edges
#define DD   64       // feature dim
#define DOUT 16       // output dim
#define CAP  64       // CSR slots per node (1 self + 63 edges; P(deg>63) ~ 1e-19)
#define WPAD 68       // padded row stride (words) for transposed W in LDS

#define BW    512                 // fused-kernel block: 8 waves amortize W LDS
#define NWAVE (BW / 64)           // 8 waves/block
#define GRIDP 1024                // persistent grid: 4 blocks/CU x 256 CU
#define TOTW  (GRIDP * NWAVE)     // 8192 striding waves

// --- binning pipeline params ---
#define EPB  8192                      // edges per block in hist/scatter
#define NBL  ((EE + EPB - 1) / EPB)    // 196 blocks
#define BSH  9                         // bucket = dst >> 9 (512 nodes/bucket)
#define NB   196                       // ceil(100000 / 512)

// ---------------------------------------------------------------------------
// K1: per-block histogram over NB dst-buckets; also zeroes cnt.
// ---------------------------------------------------------------------------
__global__ __launch_bounds__(256) void k_hist(const int* __restrict__ ei,
                                              int* __restrict__ hist,
                                              int* __restrict__ cnt) {
    for (int i = blockIdx.x * 256 + threadIdx.x; i < NN; i += NBL * 256)
        cnt[i] = 0;
    __shared__ int h[NB];
    for (int i = threadIdx.x; i < NB; i += 256) h[i] = 0;
    __syncthreads();
    int e0 = blockIdx.x * EPB;
    int e1 = min(e0 + EPB, EE);
    for (int e = e0 + (int)threadIdx.x; e < e1; e += 256) {
        int d = ei[EE + e];
        atomicAdd(&h[d >> BSH], 1);
    }
    __syncthreads();
    for (int i = threadIdx.x; i < NB; i += 256)
        hist[i * NBL + blockIdx.x] = h[i];
}

// ---------------------------------------------------------------------------
// K2: single-block exclusive scan of the NB*NBL histogram (in place); also
// zeroes the two sentinel rows (row NN of A and B).
// ---------------------------------------------------------------------------
__global__ __launch_bounds__(256) void k_scan(int* __restrict__ hist,
                                              float* __restrict__ As,
                                              float* __restrict__ Bs) {
    int t = threadIdx.x;
    if (t < DD) As[(size_t)NN * DD + t] = 0.f;
    else if (t < 2 * DD) Bs[(size_t)NN * DD + (t - DD)] = 0.f;

    const int TOT = NB * NBL;
    const int CH  = (TOT + 255) / 256;
    __shared__ int part[256];
    int lo = t * CH, hi = min(lo + CH, TOT);
    int s = 0;
    for (int i = lo; i < hi; ++i) s += hist[i];
    part[t] = s;
    __syncthreads();
    for (int off = 1; off < 256; off <<= 1) {   // Hillis-Steele inclusive
        int v = (t >= off) ? part[t - off] : 0;
        __syncthreads();
        part[t] += v;
        __syncthreads();
    }
    int base = (t == 0) ? 0 : part[t - 1];
    for (int i = lo; i < hi; ++i) {
        int v = hist[i];
        hist[i] = base;
        base += v;
    }
}

// ---------------------------------------------------------------------------
// K3: scatter edges into bucket-grouped int2(src,dst). Private (bucket,block)
// ranges -> sequential full-line 8B writes.
// ---------------------------------------------------------------------------
__global__ __launch_bounds__(256) void k_scatter(const int* __restrict__ ei,
                                                 const int* __restrict__ hist,
                                                 int2* __restrict__ bed) {
    __shared__ int cur[NB];
    for (int i = threadIdx.x; i < NB; i += 256)
        cur[i] = hist[i * NBL + blockIdx.x];
    __syncthreads();
    int e0 = blockIdx.x * EPB;
    int e1 = min(e0 + EPB, EE);
    for (int e = e0 + (int)threadIdx.x; e < e1; e += 256) {
        int s = ei[e], d = ei[EE + e];
        int p = atomicAdd(&cur[d >> BSH], 1);
        bed[p] = make_int2(s, d);
    }
}

// ---------------------------------------------------------------------------
// K4: build padded CSR bucket-by-bucket (128 KB window per bucket, L2-hot).
// ---------------------------------------------------------------------------
__global__ __launch_bounds__(256) void k_csr(const int2* __restrict__ bed,
                                             const int* __restrict__ hist,
                                             int* __restrict__ cnt,
                                             int* __restrict__ csr) {
    int b  = blockIdx.x;
    int lo = hist[b * NBL];
    int hi = (b == NB - 1) ? EE : hist[(b + 1) * NBL];
    for (int e = lo + (int)threadIdx.x; e < hi; e += 256) {
        int2 sd = bed[e];
        int pos = atomicAdd(&cnt[sd.y], 1);
        if (pos < CAP) csr[(size_t)sd.y * CAP + pos] = sd.x;
    }
}

// ---------------------------------------------------------------------------
// K5: xs[n] = x[n] * rsqrt(cnt[n]+1). Pure streaming float4 (gather
// linearity: agg(x@W1*dinv) == agg(x*dinv) @ W1 — deleted the 110us GEMM).
// ---------------------------------------------------------------------------
__global__ __launch_bounds__(256) void k_scale(const float* __restrict__ x,
                                               const int* __restrict__ cnt,
                                               float* __restrict__ xs) {
    int idx = blockIdx.x * 256 + threadIdx.x;   // one float4 per thread
    if (idx >= NN * (DD / 4)) return;
    int n = idx >> 4;
    float dv = rsqrtf((float)cnt[n] + 1.0f);
    float4 v = ((const float4*)x)[idx];
    v.x *= dv; v.y *= dv; v.z *= dv; v.w *= dv;
    ((float4*)xs)[idx] = v;
}

// ---------------------------------------------------------------------------
// Gather one node's aggregated row (features 4m..4m+3, replicated in all
// lanes after the xor-reduce). Row indices: direct global b32 loads (VMEM
// pipe). One branchless round of 8 dwordx4 covers deg<=31; rare wave-uniform
// 2nd round covers deg<=63. Row NN is a zero sentinel. Only 2 float4
// accumulators. DO NOT batch/unroll across nodes (round 6: spills to 256
// VGPR; round 9: batched matmuls re-triggered 160 MB scratch traffic).
// ---------------------------------------------------------------------------
__device__ __forceinline__ float4 gather_node(const float4* __restrict__ hpv,
                                              const int* __restrict__ crow,
                                              int n, int c, int sub, int m) {
    float4 fa = {0.f, 0.f, 0.f, 0.f}, fb = fa;
#define GROW(g, acc)                                                        \
    {                                                                       \
        int idx = 4 * (g) + sub;                                            \
        int rv  = crow[idx ? idx - 1 : 0];                                  \
        int row = (idx == 0) ? n : ((idx <= c) ? rv : NN);                  \
        float4 v = hpv[(size_t)row * 16 + m];                               \
        acc.x += v.x; acc.y += v.y; acc.z += v.z; acc.w += v.w;             \
    }
    GROW(0, fa) GROW(1, fb) GROW(2, fa) GROW(3, fb)
    GROW(4, fa) GROW(5, fb) GROW(6, fa) GROW(7, fb)
    if (c >= 32) {  // wave-uniform, P ~ 3e-4
#define GROW2(g, acc)                                                       \
        {                                                                   \
            int idx = 32 + 4 * (g) + sub;                                   \
            int rv  = crow[idx - 1];                                        \
            int row = (idx <= c) ? rv : NN;                                 \
            float4 v = hpv[(size_t)row * 16 + m];                           \
            acc.x += v.x; acc.y += v.y; acc.z += v.z; acc.w += v.w;         \
        }
        GROW2(0, fa) GROW2(1, fb) GROW2(2, fa) GROW2(3, fb)
        GROW2(4, fa) GROW2(5, fb) GROW2(6, fa) GROW2(7, fb)
#undef GROW2
    }
#undef GROW
    float4 s;
    s.x = fa.x + fb.x; s.y = fa.y + fb.y; s.z = fa.z + fb.z; s.w = fa.w + fb.w;
    s.x += __shfl_xor(s.x, 16); s.y += __shfl_xor(s.y, 16);
    s.z += __shfl_xor(s.z, 16); s.w += __shfl_xor(s.w, 16);
    s.x += __shfl_xor(s.x, 32); s.y += __shfl_xor(s.y, 32);
    s.z += __shfl_xor(s.z, 32); s.w += __shfl_xor(s.w, 32);
    return s;
}

// ---------------------------------------------------------------------------
// Stage W transposed+padded into LDS: sWt[j*WPAD + k] = W[k*64 + j].
// Stride 68 words: a 64-lane b128 column read aliases banks only 2-way (free).
// ---------------------------------------------------------------------------
__device__ __forceinline__ void stage_wt(const float* __restrict__ W,
                                         float* __restrict__ sWt,
                                         int tid, int nthr) {
    for (int i = tid; i < DD * DD; i += nthr) {
        int k = i >> 6, j = i & 63;
        sWt[j * WPAD + k] = W[i];   // coalesced global read, once per block
    }
}

// ---------------------------------------------------------------------------
// Fused layer (2,3): per-node serial loop (round-8 structure — the stable
// optimum). 512-thread blocks amortize the 17.4 KB W staging over 8 waves
// (LDS 19.5 KB -> thread-limited 4 blocks/CU = 32 waves = 100% occupancy);
// persistent grid-stride removes the block-tail quantization.
// ---------------------------------------------------------------------------
__global__ __launch_bounds__(BW, 8) void k_fused(const float* __restrict__ hp,
                                                 const int* __restrict__ csr,
                                                 const int* __restrict__ cnt,
                                                 const float* __restrict__ bias,
                                                 const float* __restrict__ Wn,
                                                 float* __restrict__ hpn) {
    __shared__ float sWt[DD * WPAD];        // 17.4 KB
    __shared__ float tbuf[NWAVE][DD];       // 2 KB
    const int lane = threadIdx.x & 63;
    const int wv   = threadIdx.x >> 6;
    const int sub  = lane >> 4;
    const int m    = lane & 15;

    stage_wt(Wn, sWt, threadIdx.x, BW);
    __syncthreads();

    const float4  bv4 = ((const float4*)bias)[m];
    const float4* hpv = (const float4*)hp;
    const float4* wcol = (const float4*)(sWt + lane * WPAD);

    const int wid = blockIdx.x * NWAVE + wv;
    for (int n = wid; n < NN; n += TOTW) {
        int c = cnt[n]; if (c > 63) c = 63;
        float dv = rsqrtf((float)cnt[n] + 1.0f);
        float4 s = gather_node(hpv, csr + (size_t)n * CAP, n, c, sub, m);
        float4 t4;
        t4.x = fmaxf(fmaf(dv, s.x, bv4.x), 0.f);
        t4.y = fmaxf(fmaf(dv, s.y, bv4.y), 0.f);
        t4.z = fmaxf(fmaf(dv, s.z, bv4.z), 0.f);
        t4.w = fmaxf(fmaf(dv, s.w, bv4.w), 0.f);

        if (sub == 0) ((float4*)tbuf[wv])[m] = t4;  // wave-private slot
        const float4* tb = (const float4*)tbuf[wv];
        float o = 0.f;
#pragma unroll
        for (int kk = 0; kk < DD / 4; ++kk) {
            float4 w = wcol[kk];   // b128, conflict-free via WPAD
            float4 q = tb[kk];     // wave-uniform -> broadcast
            o = fmaf(q.x, w.x, fmaf(q.y, w.y, fmaf(q.z, w.z, fmaf(q.w, w.w, o))));
        }
        hpn[(size_t)n * DD + lane] = o * dv;
    }
}

// ---------------------------------------------------------------------------
// Fused layer 1: aggx = gather(xs); t1 = relu(dinv*(aggx@W1) + b1);
// hp1[n] = (t1 @ W2) * dinv. LDS 38.9 KB -> 4 blocks/CU x 8 waves = 100%.
// ---------------------------------------------------------------------------
__global__ __launch_bounds__(BW, 8) void k_fused_l1(const float* __restrict__ xs,
                                                    const int* __restrict__ csr,
                                                    const int* __restrict__ cnt,
                                                    const float* __restrict__ b1,
                                                    const float* __restrict__ W1,
                                                    const float* __restrict__ W2,
                                                    float* __restrict__ hpn) {
    __shared__ float sW1t[DD * WPAD];
    __shared__ float sW2t[DD * WPAD];
    __shared__ float abuf[NWAVE][DD];
    __shared__ float tbuf[NWAVE][DD];
    const int lane = threadIdx.x & 63;
    const int wv   = threadIdx.x >> 6;
    const int sub  = lane >> 4;
    const int m    = lane & 15;

    stage_wt(W1, sW1t, threadIdx.x, BW);
    stage_wt(W2, sW2t, threadIdx.x, BW);
    __syncthreads();

    const float  b1v = b1[lane];
    const float4* hpv  = (const float4*)xs;
    const float4* w1col = (const float4*)(sW1t + lane * WPAD);
    const float4* w2col = (const float4*)(sW2t + lane * WPAD);

    const int wid = blockIdx.x * NWAVE + wv;
    for (int n = wid; n < NN; n += TOTW) {
        int c = cnt[n]; if (c > 63) c = 63;
        float dv = rsqrtf((float)cnt[n] + 1.0f);
        float4 s = gather_node(hpv, csr + (size_t)n * CAP, n, c, sub, m);
        if (sub == 0) ((float4*)abuf[wv])[m] = s;   // aggx row -> LDS

        const float4* ab = (const float4*)abuf[wv];
        float v = 0.f;
#pragma unroll
        for (int kk = 0; kk < DD / 4; ++kk) {
            float4 w = w1col[kk];
            float4 q = ab[kk];      // wave-uniform -> LDS broadcast
            v = fmaf(q.x, w.x, fmaf(q.y, w.y, fmaf(q.z, w.z, fmaf(q.w, w.w, v))));
        }
        float t1 = fmaxf(fmaf(dv, v, b1v), 0.f);

        tbuf[wv][lane] = t1;
        const float4* tb = (const float4*)tbuf[wv];
        float o = 0.f;
#pragma unroll
        for (int kk = 0; kk < DD / 4; ++kk) {
            float4 w = w2col[kk];
            float4 q = tb[kk];
            o = fmaf(q.x, w.x, fmaf(q.y, w.y, fmaf(q.z, w.z, fmaf(q.w, w.w, o))));
        }
        hpn[(size_t)n * DD + lane] = o * dv;
    }
}

// ---------------------------------------------------------------------------
// Final fused layer + FFN: t3 = relu(dinv*agg+b3); u = relu(t3@Wf1+bf1);
// out = u@Wf2 + bf2. LDS 25.6 KB -> 4 blocks/CU x 8 waves = 100%.
// ---------------------------------------------------------------------------
__global__ __launch_bounds__(BW, 8) void k_fused_ffn(const float* __restrict__ hp,
                                                     const int* __restrict__ csr,
                                                     const int* __restrict__ cnt,
                                                     const float* __restrict__ b3,
                                                     const float* __restrict__ Wf1,
                                                     const float* __restrict__ bf1,
                                                     const float* __restrict__ Wf2,
                                                     const float* __restrict__ bf2,
                                                     float* __restrict__ out) {
    __shared__ float sW1t[DD * WPAD];       // 17.4 KB
    __shared__ float sW2[DD * DOUT];        // 4 KB
    __shared__ float tbuf[NWAVE][DD];       // 2 KB
    __shared__ float ubuf[NWAVE][DD];       // 2 KB
    const int lane = threadIdx.x & 63;
    const int wv   = threadIdx.x >> 6;
    const int sub  = lane >> 4;   // also the K-quarter for the 2nd matmul
    const int m    = lane & 15;

    stage_wt(Wf1, sW1t, threadIdx.x, BW);
    for (int i = threadIdx.x; i < DD * DOUT / 4; i += BW)
        ((float4*)sW2)[i] = ((const float4*)Wf2)[i];
    __syncthreads();

    const float4 b3v4 = ((const float4*)b3)[m];
    const float  b1v  = bf1[lane];
    const float  b2v  = bf2[m];
    const float4* hpv  = (const float4*)hp;
    const float4* w1col = (const float4*)(sW1t + lane * WPAD);
    const float*  w2p   = sW2 + (sub * 16) * DOUT + m;  // (sub*16+k')*16 + m

    const int wid = blockIdx.x * NWAVE + wv;
    for (int n = wid; n < NN; n += TOTW) {
        int c = cnt[n]; if (c > 63) c = 63;
        float dv = rsqrtf((float)cnt[n] + 1.0f);
        float4 s = gather_node(hpv, csr + (size_t)n * CAP, n, c, sub, m);
        float4 t4;
        t4.x = fmaxf(fmaf(dv, s.x, b3v4.x), 0.f);
        t4.y = fmaxf(fmaf(dv, s.y, b3v4.y), 0.f);
        t4.z = fmaxf(fmaf(dv, s.z, b3v4.z), 0.f);
        t4.w = fmaxf(fmaf(dv, s.w, b3v4.w), 0.f);

        if (sub == 0) ((float4*)tbuf[wv])[m] = t4;
        const float4* tb = (const float4*)tbuf[wv];
        float u = b1v;
#pragma unroll
        for (int kk = 0; kk < DD / 4; ++kk) {
            float4 w = w1col[kk];
            float4 q = tb[kk];
            u = fmaf(q.x, w.x, fmaf(q.y, w.y, fmaf(q.z, w.z, fmaf(q.w, w.w, u))));
        }
        u = fmaxf(u, 0.f);

        // out = u @ Wf2 + bf2 : lane (sub,m) does quarter-K partial, 2 xor-reduces
        ubuf[wv][lane] = u;
        const float4* ub = (const float4*)(ubuf[wv] + sub * 16);
        float p = 0.f;
#pragma unroll
        for (int kq = 0; kq < 4; ++kq) {
            float4 z = ub[kq];
            p = fmaf(z.x, w2p[(4 * kq + 0) * DOUT],
                fmaf(z.y, w2p[(4 * kq + 1) * DOUT],
                fmaf(z.z, w2p[(4 * kq + 2) * DOUT],
                fmaf(z.w, w2p[(4 * kq + 3) * DOUT], p))));
        }
        p += __shfl_xor(p, 16);
        p += __shfl_xor(p, 32);
        if (lane < 16) out[(size_t)n * DOUT + m] = p + b2v;
    }
}

// ---------------------------------------------------------------------------
extern "C" void kernel_launch(void* const* d_in, const int* in_sizes, int n_in,
                              void* d_out, int out_size, void* d_ws, size_t ws_size,
                              hipStream_t stream) {
    const float* x   = (const float*)d_in[0];
    const int*   ei  = (const int*)d_in[1];
    const float* W1  = (const float*)d_in[2];
    const float* b1  = (const float*)d_in[3];
    const float* W2  = (const float*)d_in[4];
    const float* b2  = (const float*)d_in[5];
    const float* W3  = (const float*)d_in[6];
    const float* b3  = (const float*)d_in[7];
    const float* Wf1 = (const float*)d_in[8];
    const float* bf1 = (const float*)d_in[9];
    const float* Wf2 = (const float*)d_in[10];
    const float* bf2 = (const float*)d_in[11];
    float* out = (float*)d_out;

    char* ws = (char*)d_ws;
    auto al = [](size_t v) { return (v + 255) & ~(size_t)255; };
    size_t off = 0;
    int*   cnt  = (int*)(ws + off);   off = al(off + (size_t)NN * 4);
    int*   csr  = (int*)(ws + off);   off = al(off + (size_t)NN * CAP * 4);
    float* A    = (float*)(ws + off); off = al(off + (size_t)(NN + 1) * DD * 4);
    float* B    = (float*)(ws + off); off = al(off + (size_t)(NN + 1) * DD * 4);

    // Lifetime-disjoint aliases: binned int2 edges in A's first 12.8 MB
    // (consumed by k_csr, then overwritten by k_scale); hist matrix in B's
    // first 154 KB (consumed by k_csr, overwritten by k_fused_l1 output).
    int2* bed  = (int2*)A;
    int*  hist = (int*)B;

    k_hist<<<NBL, 256, 0, stream>>>(ei, hist, cnt);
    k_scan<<<1, 256, 0, stream>>>(hist, A, B);
    k_scatter<<<NBL, 256, 0, stream>>>(ei, hist, bed);
    k_csr<<<NB, 256, 0, stream>>>(bed, hist, cnt, csr);

    // xs = x * dinv  -> A
    k_scale<<<(NN * (DD / 4) + 255) / 256, 256, 0, stream>>>(x, cnt, A);
    // layer 1 (gather xs, @W1, relu, @W2) -> B = hp1
    k_fused_l1<<<GRIDP, BW, 0, stream>>>(A, csr, cnt, b1, W1, W2, B);
    // layer 2->3: agg(hp1)+relu+b2, then hp2 = (t@W3)*dinv -> A
    k_fused<<<GRIDP, BW, 0, stream>>>(B, csr, cnt, b2, W3, A);
    // layer 3 + FFN -> out
    k_fused_ffn<<<GRIDP, BW, 0, stream>>>(A, csr, cnt, b3, Wf1, bf1, Wf2, bf2, out);
}

// Round 11
// 519.131 us; speedup vs baseline: 2.3474x; 2.3474x over previous
//
#include <hip/hip_runtime.h>

#define NN   100000   // nodes
#define EE   1600000  // edges
#define DD   64       // feature dim
#define DOUT 16       // output dim
#define CAP  64       // CSR slots per node (1 self + 63 edges; P(deg>63) ~ 1e-19)
#define NPW  8        // nodes per wave (serial; NEVER batch gathers across nodes)
#define WPAD 68       // padded W row stride in words (multiple of 4: keeps b128 16B-aligned)

// --- binning pipeline params ---
#define EPB  8192                      // edges per block in hist/scatter
#define NBL  ((EE + EPB - 1) / EPB)    // 196 blocks
#define BSH  9                         // bucket = dst >> 9 (512 nodes/bucket)
#define NB   196                       // ceil(100000 / 512)

// ---------------------------------------------------------------------------
// K1: per-block histogram over NB dst-buckets; also zeroes cnt.
// ---------------------------------------------------------------------------
__global__ __launch_bounds__(256) void k_hist(const int* __restrict__ ei,
                                              int* __restrict__ hist,
                                              int* __restrict__ cnt) {
    for (int i = blockIdx.x * 256 + threadIdx.x; i < NN; i += NBL * 256)
        cnt[i] = 0;
    __shared__ int h[NB];
    for (int i = threadIdx.x; i < NB; i += 256) h[i] = 0;
    __syncthreads();
    int e0 = blockIdx.x * EPB;
    int e1 = min(e0 + EPB, EE);
    for (int e = e0 + (int)threadIdx.x; e < e1; e += 256) {
        int d = ei[EE + e];
        atomicAdd(&h[d >> BSH], 1);
    }
    __syncthreads();
    for (int i = threadIdx.x; i < NB; i += 256)
        hist[i * NBL + blockIdx.x] = h[i];
}

// ---------------------------------------------------------------------------
// K2: single-block exclusive scan of the NB*NBL histogram (in place); also
// zeroes the two sentinel rows (row NN of A and B).
// ---------------------------------------------------------------------------
__global__ __launch_bounds__(256) void k_scan(int* __restrict__ hist,
                                              float* __restrict__ As,
                                              float* __restrict__ Bs) {
    int t = threadIdx.x;
    if (t < DD) As[(size_t)NN * DD + t] = 0.f;
    else if (t < 2 * DD) Bs[(size_t)NN * DD + (t - DD)] = 0.f;

    const int TOT = NB * NBL;
    const int CH  = (TOT + 255) / 256;
    __shared__ int part[256];
    int lo = t * CH, hi = min(lo + CH, TOT);
    int s = 0;
    for (int i = lo; i < hi; ++i) s += hist[i];
    part[t] = s;
    __syncthreads();
    for (int off = 1; off < 256; off <<= 1) {   // Hillis-Steele inclusive
        int v = (t >= off) ? part[t - off] : 0;
        __syncthreads();
        part[t] += v;
        __syncthreads();
    }
    int base = (t == 0) ? 0 : part[t - 1];
    for (int i = lo; i < hi; ++i) {
        int v = hist[i];
        hist[i] = base;
        base += v;
    }
}

// ---------------------------------------------------------------------------
// K3: scatter edges into bucket-grouped int2(src,dst). Private (bucket,block)
// ranges -> sequential full-line 8B writes.
// ---------------------------------------------------------------------------
__global__ __launch_bounds__(256) void k_scatter(const int* __restrict__ ei,
                                                 const int* __restrict__ hist,
                                                 int2* __restrict__ bed) {
    __shared__ int cur[NB];
    for (int i = threadIdx.x; i < NB; i += 256)
        cur[i] = hist[i * NBL + blockIdx.x];
    __syncthreads();
    int e0 = blockIdx.x * EPB;
    int e1 = min(e0 + EPB, EE);
    for (int e = e0 + (int)threadIdx.x; e < e1; e += 256) {
        int s = ei[e], d = ei[EE + e];
        int p = atomicAdd(&cur[d >> BSH], 1);
        bed[p] = make_int2(s, d);
    }
}

// ---------------------------------------------------------------------------
// K4: build padded CSR bucket-by-bucket (128 KB window per bucket, L2-hot).
// ---------------------------------------------------------------------------
__global__ __launch_bounds__(256) void k_csr(const int2* __restrict__ bed,
                                             const int* __restrict__ hist,
                                             int* __restrict__ cnt,
                                             int* __restrict__ csr) {
    int b  = blockIdx.x;
    int lo = hist[b * NBL];
    int hi = (b == NB - 1) ? EE : hist[(b + 1) * NBL];
    for (int e = lo + (int)threadIdx.x; e < hi; e += 256) {
        int2 sd = bed[e];
        int pos = atomicAdd(&cnt[sd.y], 1);
        if (pos < CAP) csr[(size_t)sd.y * CAP + pos] = sd.x;
    }
}

// ---------------------------------------------------------------------------
// K5: xs[n] = x[n] * rsqrt(cnt[n]+1) = ts_0. Pure streaming float4.
// Full linearity chain: agg((t@W)*dinv) == agg(t*dinv) @ W, so every layer
// applies W once, POST-aggregation; stored rows are always t*dinv.
// ---------------------------------------------------------------------------
__global__ __launch_bounds__(256) void k_scale(const float* __restrict__ x,
                                               const int* __restrict__ cnt,
                                               float* __restrict__ xs) {
    int idx = blockIdx.x * 256 + threadIdx.x;   // one float4 per thread
    if (idx >= NN * (DD / 4)) return;
    int n = idx >> 4;
    float dv = rsqrtf((float)cnt[n] + 1.0f);
    float4 v = ((const float4*)x)[idx];
    v.x *= dv; v.y *= dv; v.z *= dv; v.w *= dv;
    ((float4*)xs)[idx] = v;
}

// ---------------------------------------------------------------------------
// Gather one node's aggregated row (features 4m..4m+3, replicated in all
// lanes after the xor-reduce). Row indices: direct global b32 loads (VMEM
// pipe). One branchless round of 8 dwordx4 covers deg<=31; rare wave-uniform
// 2nd round covers deg<=63. Row NN is a zero sentinel. Only 2 float4
// accumulators — needs ~52 VGPRs free. NEVER batch/unroll across nodes
// (round 6: 256-VGPR spills) and NEVER squeeze the VGPR budget below 64
// (round 10: launch_bounds(512,8) -> 32 VGPR -> 1.3 GB scratch traffic).
// ---------------------------------------------------------------------------
__device__ __forceinline__ float4 gather_node(const float4* __restrict__ hpv,
                                              const int* __restrict__ crow,
                                              int n, int c, int sub, int m) {
    float4 fa = {0.f, 0.f, 0.f, 0.f}, fb = fa;
#define GROW(g, acc)                                                        \
    {                                                                       \
        int idx = 4 * (g) + sub;                                            \
        int rv  = crow[idx ? idx - 1 : 0];                                  \
        int row = (idx == 0) ? n : ((idx <= c) ? rv : NN);                  \
        float4 v = hpv[(size_t)row * 16 + m];                               \
        acc.x += v.x; acc.y += v.y; acc.z += v.z; acc.w += v.w;             \
    }
    GROW(0, fa) GROW(1, fb) GROW(2, fa) GROW(3, fb)
    GROW(4, fa) GROW(5, fb) GROW(6, fa) GROW(7, fb)
    if (c >= 32) {  // wave-uniform, P ~ 3e-4
#define GROW2(g, acc)                                                       \
        {                                                                   \
            int idx = 32 + 4 * (g) + sub;                                   \
            int rv  = crow[idx - 1];                                        \
            int row = (idx <= c) ? rv : NN;                                 \
            float4 v = hpv[(size_t)row * 16 + m];                           \
            acc.x += v.x; acc.y += v.y; acc.z += v.z; acc.w += v.w;         \
        }
        GROW2(0, fa) GROW2(1, fb) GROW2(2, fa) GROW2(3, fb)
        GROW2(4, fa) GROW2(5, fb) GROW2(6, fa) GROW2(7, fb)
#undef GROW2
    }
#undef GROW
    float4 s;
    s.x = fa.x + fb.x; s.y = fa.y + fb.y; s.z = fa.z + fb.z; s.w = fa.w + fb.w;
    s.x += __shfl_xor(s.x, 16); s.y += __shfl_xor(s.y, 16);
    s.z += __shfl_xor(s.z, 16); s.w += __shfl_xor(s.w, 16);
    s.x += __shfl_xor(s.x, 32); s.y += __shfl_xor(s.y, 32);
    s.z += __shfl_xor(s.z, 32); s.w += __shfl_xor(s.w, 32);
    return s;
}

// ---------------------------------------------------------------------------
// Stage W transposed+padded into LDS: sWt[j*WPAD + k] = W[k*64 + j].
// Stride 68 words keeps b128 column reads 16B-aligned and conflict-cheap.
// ---------------------------------------------------------------------------
__device__ __forceinline__ void stage_wt(const float* __restrict__ W,
                                         float* __restrict__ sWt, int tid) {
    for (int i = tid; i < DD * DD; i += 256) {
        int k = i >> 6, j = i & 63;
        sWt[j * WPAD + k] = W[i];   // coalesced global read, once per block
    }
}

// ---------------------------------------------------------------------------
// One GCN layer (used 3x): agg = gather(ts_in);  t = relu(dinv*(agg@W) + b);
// out = t * (scale_out ? dinv : 1).   LDS = 17.4K (W) + 1K = 18.4K ->
// 8 blocks/CU x 4 waves = 32 waves/CU (100%); VGPR ~52 fits the (256,8)
// budget of 64 (proven by round-8 k_fused at 48-52).
// ---------------------------------------------------------------------------
__global__ __launch_bounds__(256, 8) void k_layer(const float* __restrict__ tsin,
                                                  const int* __restrict__ csr,
                                                  const int* __restrict__ cnt,
                                                  const float* __restrict__ bias,
                                                  const float* __restrict__ W,
                                                  const int scale_out,
                                                  float* __restrict__ outp) {
    __shared__ float sWt[DD * WPAD];     // 17408 B
    __shared__ float abuf[4][DD];        // 1024 B
    const int lane = threadIdx.x & 63;
    const int wv   = threadIdx.x >> 6;
    const int sub  = lane >> 4;
    const int m    = lane & 15;

    stage_wt(W, sWt, threadIdx.x);
    __syncthreads();

    const float bv = bias[lane];
    const float4* hpv  = (const float4*)tsin;
    const float4* wcol = (const float4*)(sWt + lane * WPAD);

    int base = (blockIdx.x * 4 + wv) * NPW;   // 3125 blocks * 32 = 100000 exact
    for (int r = 0; r < NPW; ++r) {
        int n = base + r;
        if (n >= NN) return;
        int c = cnt[n]; if (c > 63) c = 63;
        float dv = rsqrtf((float)cnt[n] + 1.0f);
        float4 s = gather_node(hpv, csr + (size_t)n * CAP, n, c, sub, m);
        if (sub == 0) ((float4*)abuf[wv])[m] = s;   // agg row -> wave slot

        const float4* ab = (const float4*)abuf[wv];
        float o = 0.f;
#pragma unroll
        for (int kk = 0; kk < DD / 4; ++kk) {
            float4 w = wcol[kk];   // b128 column read, conflict-cheap via WPAD
            float4 q = ab[kk];     // wave-uniform -> LDS broadcast
            o = fmaf(q.x, w.x, fmaf(q.y, w.y, fmaf(q.z, w.z, fmaf(q.w, w.w, o))));
        }
        float t = fmaxf(fmaf(dv, o, bv), 0.f);
        float dvout = scale_out ? dv : 1.0f;   // wave-uniform cndmask
        outp[(size_t)n * DD + lane] = t * dvout;
    }
}

// ---------------------------------------------------------------------------
// Dense FFN (no gather): u = relu(t3@Wf1 + bf1); out = u@Wf2 + bf2.
// Wf1 in LDS (b128 columns); Wf2 in 16 VGPRs/lane (proven round 4).
// LDS 18.4K -> 8 blocks/CU.
// ---------------------------------------------------------------------------
__global__ __launch_bounds__(256, 8) void k_ffn(const float* __restrict__ t3,
                                                const float* __restrict__ Wf1,
                                                const float* __restrict__ bf1,
                                                const float* __restrict__ Wf2,
                                                const float* __restrict__ bf2,
                                                float* __restrict__ out) {
    __shared__ float sW1t[DD * WPAD];    // 17408 B
    __shared__ float tbuf[4][DD];        // 1024 B (t rows, then u rows)
    const int lane = threadIdx.x & 63;
    const int wv   = threadIdx.x >> 6;
    const int sub  = lane >> 4;   // K-quarter for the 2nd matmul
    const int m    = lane & 15;

    stage_wt(Wf1, sW1t, threadIdx.x);
    __syncthreads();

    float W2reg[16];
#pragma unroll
    for (int kk = 0; kk < 16; ++kk) W2reg[kk] = Wf2[(sub * 16 + kk) * DOUT + m];
    const float b1v = bf1[lane];
    const float b2v = bf2[m];
    const float4* w1col = (const float4*)(sW1t + lane * WPAD);

    int base = (blockIdx.x * 4 + wv) * NPW;
    for (int r = 0; r < NPW; ++r) {
        int n = base + r;
        if (n >= NN) return;
        tbuf[wv][lane] = t3[(size_t)n * DD + lane];  // coalesced row load
        const float4* tb = (const float4*)tbuf[wv];
        float u = b1v;
#pragma unroll
        for (int kk = 0; kk < DD / 4; ++kk) {
            float4 w = w1col[kk];
            float4 q = tb[kk];
            u = fmaf(q.x, w.x, fmaf(q.y, w.y, fmaf(q.z, w.z, fmaf(q.w, w.w, u))));
        }
        u = fmaxf(u, 0.f);

        tbuf[wv][lane] = u;   // overwrite (wave-private; lgkmcnt orders RAW)
        const float4* ub = (const float4*)(tbuf[wv] + sub * 16);
        float p = 0.f;
#pragma unroll
        for (int kq = 0; kq < 4; ++kq) {
            float4 z = ub[kq];
            p = fmaf(z.x, W2reg[4 * kq + 0],
                fmaf(z.y, W2reg[4 * kq + 1],
                fmaf(z.z, W2reg[4 * kq + 2],
                fmaf(z.w, W2reg[4 * kq + 3], p))));
        }
        p += __shfl_xor(p, 16);
        p += __shfl_xor(p, 32);
        if (lane < 16) out[(size_t)n * DOUT + m] = p + b2v;
    }
}

// ---------------------------------------------------------------------------
extern "C" void kernel_launch(void* const* d_in, const int* in_sizes, int n_in,
                              void* d_out, int out_size, void* d_ws, size_t ws_size,
                              hipStream_t stream) {
    const float* x   = (const float*)d_in[0];
    const int*   ei  = (const int*)d_in[1];
    const float* W1  = (const float*)d_in[2];
    const float* b1  = (const float*)d_in[3];
    const float* W2  = (const float*)d_in[4];
    const float* b2  = (const float*)d_in[5];
    const float* W3  = (const float*)d_in[6];
    const float* b3  = (const float*)d_in[7];
    const float* Wf1 = (const float*)d_in[8];
    const float* bf1 = (const float*)d_in[9];
    const float* Wf2 = (const float*)d_in[10];
    const float* bf2 = (const float*)d_in[11];
    float* out = (float*)d_out;

    char* ws = (char*)d_ws;
    auto al = [](size_t v) { return (v + 255) & ~(size_t)255; };
    size_t off = 0;
    int*   cnt  = (int*)(ws + off);   off = al(off + (size_t)NN * 4);
    int*   csr  = (int*)(ws + off);   off = al(off + (size_t)NN * CAP * 4);
    float* A    = (float*)(ws + off); off = al(off + (size_t)(NN + 1) * DD * 4);
    float* B    = (float*)(ws + off); off = al(off + (size_t)(NN + 1) * DD * 4);

    // Lifetime-disjoint aliases: binned int2 edges in A's first 12.8 MB
    // (consumed by k_csr, then overwritten by k_scale); hist matrix in B's
    // first 154 KB (consumed by k_csr, overwritten by k_layer #1 output).
    int2* bed  = (int2*)A;
    int*  hist = (int*)B;

    k_hist<<<NBL, 256, 0, stream>>>(ei, hist, cnt);
    k_scan<<<1, 256, 0, stream>>>(hist, A, B);
    k_scatter<<<NBL, 256, 0, stream>>>(ei, hist, bed);
    k_csr<<<NB, 256, 0, stream>>>(bed, hist, cnt, csr);

    int gf = NN / (4 * NPW);                       // 3125 blocks, exact cover

    // ts0 = x * dinv -> A
    k_scale<<<(NN * (DD / 4) + 255) / 256, 256, 0, stream>>>(x, cnt, A);
    // layer 1: ts1 = relu(dinv*(agg(ts0)@W1)+b1)*dinv -> B
    k_layer<<<gf, 256, 0, stream>>>(A, csr, cnt, b1, W1, 1, B);
    // layer 2: ts2 -> A
    k_layer<<<gf, 256, 0, stream>>>(B, csr, cnt, b2, W2, 1, A);
    // layer 3: t3 (UNSCALED, feeds FFN) -> B
    k_layer<<<gf, 256, 0, stream>>>(A, csr, cnt, b3, W3, 0, B);
    // FFN: out = relu(t3@Wf1+bf1)@Wf2 + bf2
    k_ffn<<<gf, 256, 0, stream>>>(B, Wf1, bf1, Wf2, bf2, out);
}

// Round 12
// 427.476 us; speedup vs baseline: 2.8507x; 1.2144x over previous
//
#include <hip/hip_runtime.h>

#define NN   100000   // nodes
#define EE   1600000  // edges
#define DD   64       // feature dim
#define DOUT 16       // output dim
#define CAP  64       // CSR slots per node (1 self + 63 edges; P(deg>63) ~ 1e-19)
#define NPW  8        // nodes per wave (serial; NEVER batch gathers across nodes)
#define WPAD 68       // padded W row stride in words (multiple of 4: b128 16B-aligned)

// --- build params ---
#define BSH  9                         // bucket = dst >> 9 (512 nodes/bucket)
#define NB   196                       // ceil(100000 / 512)
#define BCAP 10240                     // slots per bucket (Poisson(8192) + 22 sigma)
#define EPB  2048                      // edges per scatter block
#define NBL  ((EE + EPB - 1) / EPB)    // 782 scatter blocks

// ---------------------------------------------------------------------------
// Build K1: one-pass binning scatter. Per block: LDS histogram of its 2048
// edges -> ONE global atomicAdd per (block,bucket) reserves a range in the
// bucket's fixed BCAP region -> LDS cursors -> write int2(src,dst).
// Replaces hist+scan+scatter (the single-block serial scan was a build
// bottleneck). gcur must be pre-zeroed.
// ---------------------------------------------------------------------------
__global__ __launch_bounds__(256) void k_scatter2(const int* __restrict__ ei,
                                                  int* __restrict__ gcur,
                                                  int2* __restrict__ bed) {
    __shared__ int h[NB];
    __shared__ int cur[NB];
    for (int i = threadIdx.x; i < NB; i += 256) h[i] = 0;
    __syncthreads();
    int e0 = blockIdx.x * EPB;
    int e1 = min(e0 + EPB, EE);
    for (int e = e0 + (int)threadIdx.x; e < e1; e += 256)
        atomicAdd(&h[ei[EE + e] >> BSH], 1);
    __syncthreads();
    for (int i = threadIdx.x; i < NB; i += 256)
        cur[i] = i * BCAP + (h[i] ? atomicAdd(&gcur[i], h[i]) : 0);
    __syncthreads();
    for (int e = e0 + (int)threadIdx.x; e < e1; e += 256) {
        int s = ei[e], d = ei[EE + e];
        int b = d >> BSH;
        int p = atomicAdd(&cur[b], 1);
        if (p < (b + 1) * BCAP) bed[p] = make_int2(s, d);  // 22-sigma guard
    }
}

// ---------------------------------------------------------------------------
// Build K2: padded CSR, one 1024-thread block per bucket (128 KB window
// stays XCD-local; 4x the parallelism of 256 threads). cnt pre-zeroed.
// ---------------------------------------------------------------------------
__global__ __launch_bounds__(1024) void k_csr(const int2* __restrict__ bed,
                                              const int* __restrict__ gcur,
                                              int* __restrict__ cnt,
                                              int* __restrict__ csr) {
    int b  = blockIdx.x;
    int lo = b * BCAP;
    int hi = lo + min(gcur[b], BCAP);
    for (int e = lo + (int)threadIdx.x; e < hi; e += 1024) {
        int2 sd = bed[e];
        int pos = atomicAdd(&cnt[sd.y], 1);
        if (pos < CAP) csr[(size_t)sd.y * CAP + pos] = sd.x;
    }
}

// ---------------------------------------------------------------------------
// K3: ts0[n] = x[n] * rsqrt(cnt[n]+1). Pure streaming float4.
// Full linearity chain: agg((t@W)*dinv) == agg(t*dinv) @ W, so every layer
// applies W once, POST-aggregation; stored rows are always t*dinv.
// ---------------------------------------------------------------------------
__global__ __launch_bounds__(256) void k_scale(const float* __restrict__ x,
                                               const int* __restrict__ cnt,
                                               float* __restrict__ xs) {
    int idx = blockIdx.x * 256 + threadIdx.x;   // one float4 per thread
    if (idx >= NN * (DD / 4)) return;
    int n = idx >> 4;
    float dv = rsqrtf((float)cnt[n] + 1.0f);
    float4 v = ((const float4*)x)[idx];
    v.x *= dv; v.y *= dv; v.z *= dv; v.w *= dv;
    ((float4*)xs)[idx] = v;
}

// ---------------------------------------------------------------------------
// Gather one node's aggregated row (features 4m..4m+3, replicated in all
// lanes after the xor-reduce). Row indices: direct global b32 loads (VMEM
// pipe). One branchless round of 8 dwordx4 covers deg<=31; rare wave-uniform
// 2nd round covers deg<=63. Row NN is a zero sentinel. Needs ~52 free VGPRs
// to keep all 8 loads in flight:
//   - round 6/9: batching nodes -> 256 VGPR -> scratch spills (2x slower)
//   - round 10: (512,8) budget 64 -> 32 VGPR -> 1.3 GB spill traffic
//   - round 11: (256,8) budget 64 -> 32 VGPR, no spills but loads
//     SERIALIZED (2-4 in flight) -> latency doubles, occupancy gain wasted
// Proven operating point: __launch_bounds__(256,4) -> VGPR ~52 (round 8).
// ---------------------------------------------------------------------------
__device__ __forceinline__ float4 gather_node(const float4* __restrict__ hpv,
                                              const int* __restrict__ crow,
                                              int n, int c, int sub, int m) {
    float4 fa = {0.f, 0.f, 0.f, 0.f}, fb = fa;
#define GROW(g, acc)                                                        \
    {                                                                       \
        int idx = 4 * (g) + sub;                                            \
        int rv  = crow[idx ? idx - 1 : 0];                                  \
        int row = (idx == 0) ? n : ((idx <= c) ? rv : NN);                  \
        float4 v = hpv[(size_t)row * 16 + m];                               \
        acc.x += v.x; acc.y += v.y; acc.z += v.z; acc.w += v.w;             \
    }
    GROW(0, fa) GROW(1, fb) GROW(2, fa) GROW(3, fb)
    GROW(4, fa) GROW(5, fb) GROW(6, fa) GROW(7, fb)
    if (c >= 32) {  // wave-uniform, P ~ 3e-4
#define GROW2(g, acc)                                                       \
        {                                                                   \
            int idx = 32 + 4 * (g) + sub;                                   \
            int rv  = crow[idx - 1];                                        \
            int row = (idx <= c) ? rv : NN;                                 \
            float4 v = hpv[(size_t)row * 16 + m];                           \
            acc.x += v.x; acc.y += v.y; acc.z += v.z; acc.w += v.w;         \
        }
        GROW2(0, fa) GROW2(1, fb) GROW2(2, fa) GROW2(3, fb)
        GROW2(4, fa) GROW2(5, fb) GROW2(6, fa) GROW2(7, fb)
#undef GROW2
    }
#undef GROW
    float4 s;
    s.x = fa.x + fb.x; s.y = fa.y + fb.y; s.z = fa.z + fb.z; s.w = fa.w + fb.w;
    s.x += __shfl_xor(s.x, 16); s.y += __shfl_xor(s.y, 16);
    s.z += __shfl_xor(s.z, 16); s.w += __shfl_xor(s.w, 16);
    s.x += __shfl_xor(s.x, 32); s.y += __shfl_xor(s.y, 32);
    s.z += __shfl_xor(s.z, 32); s.w += __shfl_xor(s.w, 32);
    return s;
}

// ---------------------------------------------------------------------------
// Stage W transposed+padded into LDS: sWt[j*WPAD + k] = W[k*64 + j].
// ---------------------------------------------------------------------------
__device__ __forceinline__ void stage_wt(const float* __restrict__ W,
                                         float* __restrict__ sWt, int tid) {
    for (int i = tid; i < DD * DD; i += 256) {
        int k = i >> 6, j = i & 63;
        sWt[j * WPAD + k] = W[i];   // coalesced global read, once per block
    }
}

// ---------------------------------------------------------------------------
// One GCN layer (used 3x): agg = gather(ts_in);  t = relu(dinv*(agg@W) + b);
// out = t * (scale_out ? dinv : 1).
// LDS 18.4 KB -> 8 blocks/CU possible; (256,4) budget 128 lets the compiler
// keep the gather's 8 loads in flight at ~52 VGPR -> 8 blocks = 32 waves/CU.
// ---------------------------------------------------------------------------
__global__ __launch_bounds__(256, 4) void k_layer(const float* __restrict__ tsin,
                                                  const int* __restrict__ csr,
                                                  const int* __restrict__ cnt,
                                                  const float* __restrict__ bias,
                                                  const float* __restrict__ W,
                                                  const int scale_out,
                                                  float* __restrict__ outp) {
    __shared__ float sWt[DD * WPAD];     // 17408 B
    __shared__ float abuf[4][DD];        // 1024 B
    const int lane = threadIdx.x & 63;
    const int wv   = threadIdx.x >> 6;
    const int sub  = lane >> 4;
    const int m    = lane & 15;

    stage_wt(W, sWt, threadIdx.x);
    __syncthreads();

    const float bv = bias[lane];
    const float4* hpv  = (const float4*)tsin;
    const float4* wcol = (const float4*)(sWt + lane * WPAD);

    int base = (blockIdx.x * 4 + wv) * NPW;   // 3125 blocks * 32 = 100000 exact
    for (int r = 0; r < NPW; ++r) {
        int n = base + r;
        if (n >= NN) return;
        int c = cnt[n]; if (c > 63) c = 63;
        float dv = rsqrtf((float)cnt[n] + 1.0f);
        float4 s = gather_node(hpv, csr + (size_t)n * CAP, n, c, sub, m);
        if (sub == 0) ((float4*)abuf[wv])[m] = s;   // agg row -> wave slot

        const float4* ab = (const float4*)abuf[wv];
        float o = 0.f;
#pragma unroll
        for (int kk = 0; kk < DD / 4; ++kk) {
            float4 w = wcol[kk];   // b128 column read, conflict-cheap via WPAD
            float4 q = ab[kk];     // wave-uniform -> LDS broadcast
            o = fmaf(q.x, w.x, fmaf(q.y, w.y, fmaf(q.z, w.z, fmaf(q.w, w.w, o))));
        }
        float t = fmaxf(fmaf(dv, o, bv), 0.f);
        float dvout = scale_out ? dv : 1.0f;   // wave-uniform cndmask
        outp[(size_t)n * DD + lane] = t * dvout;
    }
}

// ---------------------------------------------------------------------------
// Dense FFN (no gather): u = relu(t3@Wf1 + bf1); out = u@Wf2 + bf2.
// Wf1 in LDS (b128 columns); Wf2 in 16 VGPRs/lane.
// ---------------------------------------------------------------------------
__global__ __launch_bounds__(256, 4) void k_ffn(const float* __restrict__ t3,
                                                const float* __restrict__ Wf1,
                                                const float* __restrict__ bf1,
                                                const float* __restrict__ Wf2,
                                                const float* __restrict__ bf2,
                                                float* __restrict__ out) {
    __shared__ float sW1t[DD * WPAD];    // 17408 B
    __shared__ float tbuf[4][DD];        // 1024 B (t rows, then u rows)
    const int lane = threadIdx.x & 63;
    const int wv   = threadIdx.x >> 6;
    const int sub  = lane >> 4;   // K-quarter for the 2nd matmul
    const int m    = lane & 15;

    stage_wt(Wf1, sW1t, threadIdx.x);
    __syncthreads();

    float W2reg[16];
#pragma unroll
    for (int kk = 0; kk < 16; ++kk) W2reg[kk] = Wf2[(sub * 16 + kk) * DOUT + m];
    const float b1v = bf1[lane];
    const float b2v = bf2[m];
    const float4* w1col = (const float4*)(sW1t + lane * WPAD);

    int base = (blockIdx.x * 4 + wv) * NPW;
    for (int r = 0; r < NPW; ++r) {
        int n = base + r;
        if (n >= NN) return;
        tbuf[wv][lane] = t3[(size_t)n * DD + lane];  // coalesced row load
        const float4* tb = (const float4*)tbuf[wv];
        float u = b1v;
#pragma unroll
        for (int kk = 0; kk < DD / 4; ++kk) {
            float4 w = w1col[kk];
            float4 q = tb[kk];
            u = fmaf(q.x, w.x, fmaf(q.y, w.y, fmaf(q.z, w.z, fmaf(q.w, w.w, u))));
        }
        u = fmaxf(u, 0.f);

        tbuf[wv][lane] = u;   // overwrite (wave-private; lgkmcnt orders RAW)
        const float4* ub = (const float4*)(tbuf[wv] + sub * 16);
        float p = 0.f;
#pragma unroll
        for (int kq = 0; kq < 4; ++kq) {
            float4 z = ub[kq];
            p = fmaf(z.x, W2reg[4 * kq + 0],
                fmaf(z.y, W2reg[4 * kq + 1],
                fmaf(z.z, W2reg[4 * kq + 2],
                fmaf(z.w, W2reg[4 * kq + 3], p))));
        }
        p += __shfl_xor(p, 16);
        p += __shfl_xor(p, 32);
        if (lane < 16) out[(size_t)n * DOUT + m] = p + b2v;
    }
}

// ---------------------------------------------------------------------------
extern "C" void kernel_launch(void* const* d_in, const int* in_sizes, int n_in,
                              void* d_out, int out_size, void* d_ws, size_t ws_size,
                              hipStream_t stream) {
    const float* x   = (const float*)d_in[0];
    const int*   ei  = (const int*)d_in[1];
    const float* W1  = (const float*)d_in[2];
    const float* b1  = (const float*)d_in[3];
    const float* W2  = (const float*)d_in[4];
    const float* b2  = (const float*)d_in[5];
    const float* W3  = (const float*)d_in[6];
    const float* b3  = (const float*)d_in[7];
    const float* Wf1 = (const float*)d_in[8];
    const float* bf1 = (const float*)d_in[9];
    const float* Wf2 = (const float*)d_in[10];
    const float* bf2 = (const float*)d_in[11];
    float* out = (float*)d_out;

    char* ws = (char*)d_ws;
    auto al = [](size_t v) { return (v + 255) & ~(size_t)255; };
    size_t off = 0;
    int*   cnt  = (int*)(ws + off);   off = al(off + (size_t)NN * 4);
    int*   gcur = (int*)(ws + off);   off = al(off + (size_t)NB * 4);
    int*   csr  = (int*)(ws + off);   off = al(off + (size_t)NN * CAP * 4);
    float* A    = (float*)(ws + off); off = al(off + (size_t)(NN + 1) * DD * 4);
    float* B    = (float*)(ws + off); off = al(off + (size_t)(NN + 1) * DD * 4);

    // Lifetime-disjoint alias: bed (196*10240 int2 = 16.06 MB) in A's first
    // 16.1 MB — consumed by k_csr, then A is overwritten by k_scale.
    int2* bed = (int2*)A;

    hipMemsetAsync(cnt, 0, (size_t)NN * 4, stream);
    hipMemsetAsync(gcur, 0, (size_t)NB * 4, stream);
    hipMemsetAsync(A + (size_t)NN * DD, 0, DD * 4, stream);  // zero sentinel rows
    hipMemsetAsync(B + (size_t)NN * DD, 0, DD * 4, stream);

    k_scatter2<<<NBL, 256, 0, stream>>>(ei, gcur, bed);
    k_csr<<<NB, 1024, 0, stream>>>(bed, gcur, cnt, csr);

    int gf = NN / (4 * NPW);                       // 3125 blocks, exact cover

    // ts0 = x * dinv -> A   (overwrites bed)
    k_scale<<<(NN * (DD / 4) + 255) / 256, 256, 0, stream>>>(x, cnt, A);
    // layer 1: ts1 = relu(dinv*(agg(ts0)@W1)+b1)*dinv -> B
    k_layer<<<gf, 256, 0, stream>>>(A, csr, cnt, b1, W1, 1, B);
    // layer 2: ts2 -> A
    k_layer<<<gf, 256, 0, stream>>>(B, csr, cnt, b2, W2, 1, A);
    // layer 3: t3 (UNSCALED, feeds FFN) -> B
    k_layer<<<gf, 256, 0, stream>>>(A, csr, cnt, b3, W3, 0, B);
    // FFN: out = relu(t3@Wf1+bf1)@Wf2 + bf2
    k_ffn<<<gf, 256, 0, stream>>>(B, Wf1, bf1, Wf2, bf2, out);
}

// Round 13
// 426.224 us; speedup vs baseline: 2.8591x; 1.0029x over previous
//
#include <hip/hip_runtime.h>

#define NN   100000   // nodes
#define EE   1600000  // edges
#define DD   64       // feature dim
#define DOUT 16       // output dim
#define CAP  64       // CSR slots per node (1 self + 63 edges; P(deg>63) ~ 1e-19)
#define NPW  8        // nodes per wave (gather strictly serial; matmul batched)
#define WPAD 68       // padded W row stride in words (multiple of 4: b128 16B-aligned)

// --- build params ---
#define BSH  9                         // bucket = dst >> 9 (512 nodes/bucket)
#define NB   196                       // ceil(100000 / 512)
#define BCAP 10240                     // slots per bucket (Poisson(8192) + 22 sigma)
#define EPB  2048                      // edges per scatter block
#define NBL  ((EE + EPB - 1) / EPB)    // 782 scatter blocks

// ---------------------------------------------------------------------------
// Build K1: one-pass binning scatter. Per block: LDS histogram of its 2048
// edges -> ONE global atomicAdd per (block,bucket) reserves a range in the
// bucket's fixed BCAP region -> LDS cursors -> write int2(src,dst).
// ---------------------------------------------------------------------------
__global__ __launch_bounds__(256) void k_scatter2(const int* __restrict__ ei,
                                                  int* __restrict__ gcur,
                                                  int2* __restrict__ bed) {
    __shared__ int h[NB];
    __shared__ int cur[NB];
    for (int i = threadIdx.x; i < NB; i += 256) h[i] = 0;
    __syncthreads();
    int e0 = blockIdx.x * EPB;
    int e1 = min(e0 + EPB, EE);
    for (int e = e0 + (int)threadIdx.x; e < e1; e += 256)
        atomicAdd(&h[ei[EE + e] >> BSH], 1);
    __syncthreads();
    for (int i = threadIdx.x; i < NB; i += 256)
        cur[i] = i * BCAP + (h[i] ? atomicAdd(&gcur[i], h[i]) : 0);
    __syncthreads();
    for (int e = e0 + (int)threadIdx.x; e < e1; e += 256) {
        int s = ei[e], d = ei[EE + e];
        int b = d >> BSH;
        int p = atomicAdd(&cur[b], 1);
        if (p < (b + 1) * BCAP) bed[p] = make_int2(s, d);  // 22-sigma guard
    }
}

// ---------------------------------------------------------------------------
// Build K2: padded CSR, one 1024-thread block per bucket (128 KB window
// stays XCD-local). cnt pre-zeroed.
// ---------------------------------------------------------------------------
__global__ __launch_bounds__(1024) void k_csr(const int2* __restrict__ bed,
                                              const int* __restrict__ gcur,
                                              int* __restrict__ cnt,
                                              int* __restrict__ csr) {
    int b  = blockIdx.x;
    int lo = b * BCAP;
    int hi = lo + min(gcur[b], BCAP);
    for (int e = lo + (int)threadIdx.x; e < hi; e += 1024) {
        int2 sd = bed[e];
        int pos = atomicAdd(&cnt[sd.y], 1);
        if (pos < CAP) csr[(size_t)sd.y * CAP + pos] = sd.x;
    }
}

// ---------------------------------------------------------------------------
// K3: ts0[n] = x[n] * rsqrt(cnt[n]+1). Pure streaming float4.
// Full linearity chain: agg((t@W)*dinv) == agg(t*dinv) @ W, so every layer
// applies W once, POST-aggregation; stored rows are always t*dinv.
// ---------------------------------------------------------------------------
__global__ __launch_bounds__(256) void k_scale(const float* __restrict__ x,
                                               const int* __restrict__ cnt,
                                               float* __restrict__ xs) {
    int idx = blockIdx.x * 256 + threadIdx.x;   // one float4 per thread
    if (idx >= NN * (DD / 4)) return;
    int n = idx >> 4;
    float dv = rsqrtf((float)cnt[n] + 1.0f);
    float4 v = ((const float4*)x)[idx];
    v.x *= dv; v.y *= dv; v.z *= dv; v.w *= dv;
    ((float4*)xs)[idx] = v;
}

// ---------------------------------------------------------------------------
// Gather one node's aggregated row (features 4m..4m+3, replicated in all
// lanes after the xor-reduce). Row indices: direct global b32 loads (VMEM
// pipe). One branchless round of 8 dwordx4 covers deg<=31; rare wave-uniform
// 2nd round covers deg<=63. Row NN is a zero sentinel. Needs ~52 free VGPRs
// to keep all 8 loads in flight:
//   - round 6/9: batching GATHERS across nodes -> 256 VGPR -> spills
//   - round 10: (512,8) budget 64 -> 32 VGPR -> 1.3 GB spill traffic
//   - round 11: (256,8) budget 64 -> 32 VGPR, loads serialized, no net win
// Proven operating point: __launch_bounds__(256,4), serial per-node calls.
// ---------------------------------------------------------------------------
__device__ __forceinline__ float4 gather_node(const float4* __restrict__ hpv,
                                              const int* __restrict__ crow,
                                              int n, int c, int sub, int m) {
    float4 fa = {0.f, 0.f, 0.f, 0.f}, fb = fa;
#define GROW(g, acc)                                                        \
    {                                                                       \
        int idx = 4 * (g) + sub;                                            \
        int rv  = crow[idx ? idx - 1 : 0];                                  \
        int row = (idx == 0) ? n : ((idx <= c) ? rv : NN);                  \
        float4 v = hpv[(size_t)row * 16 + m];                               \
        acc.x += v.x; acc.y += v.y; acc.z += v.z; acc.w += v.w;             \
    }
    GROW(0, fa) GROW(1, fb) GROW(2, fa) GROW(3, fb)
    GROW(4, fa) GROW(5, fb) GROW(6, fa) GROW(7, fb)
    if (c >= 32) {  // wave-uniform, P ~ 3e-4
#define GROW2(g, acc)                                                       \
        {                                                                   \
            int idx = 32 + 4 * (g) + sub;                                   \
            int rv  = crow[idx - 1];                                        \
            int row = (idx <= c) ? rv : NN;                                 \
            float4 v = hpv[(size_t)row * 16 + m];                           \
            acc.x += v.x; acc.y += v.y; acc.z += v.z; acc.w += v.w;         \
        }
        GROW2(0, fa) GROW2(1, fb) GROW2(2, fa) GROW2(3, fb)
        GROW2(4, fa) GROW2(5, fb) GROW2(6, fa) GROW2(7, fb)
#undef GROW2
    }
#undef GROW
    float4 s;
    s.x = fa.x + fb.x; s.y = fa.y + fb.y; s.z = fa.z + fb.z; s.w = fa.w + fb.w;
    s.x += __shfl_xor(s.x, 16); s.y += __shfl_xor(s.y, 16);
    s.z += __shfl_xor(s.z, 16); s.w += __shfl_xor(s.w, 16);
    s.x += __shfl_xor(s.x, 32); s.y += __shfl_xor(s.y, 32);
    s.z += __shfl_xor(s.z, 32); s.w += __shfl_xor(s.w, 32);
    return s;
}

// ---------------------------------------------------------------------------
// Stage W transposed+padded into LDS: sWt[j*WPAD + k] = W[k*64 + j].
// ---------------------------------------------------------------------------
__device__ __forceinline__ void stage_wt(const float* __restrict__ W,
                                         float* __restrict__ sWt, int tid) {
    for (int i = tid; i < DD * DD; i += 256) {
        int k = i >> 6, j = i & 63;
        sWt[j * WPAD + k] = W[i];   // coalesced global read, once per block
    }
}

// ---------------------------------------------------------------------------
// One GCN layer (used 3x): serial gather phase stashes NPW agg rows in
// wave-private LDS, then ONE batched matmul phase reads each W b128 once per
// NPW nodes (W LDS cost 16 -> 2 reads/node; round-12 counters showed the
// W-column reads were the largest LDS-pipe term at ~192 cyc/node).
// t = relu(dinv*(agg@W) + b); out = t * (scale_out ? dinv : 1).
// LDS 25.4 KB -> 6 blocks/CU; (256,4) budget 128 keeps gather's 8 loads in
// flight (~52 VGPR) with headroom for o[NPW] in the matmul phase.
// ---------------------------------------------------------------------------
__global__ __launch_bounds__(256, 4) void k_layer(const float* __restrict__ tsin,
                                                  const int* __restrict__ csr,
                                                  const int* __restrict__ cnt,
                                                  const float* __restrict__ bias,
                                                  const float* __restrict__ W,
                                                  const int scale_out,
                                                  float* __restrict__ outp) {
    __shared__ float sWt[DD * WPAD];     // 17408 B
    __shared__ float abuf[4][NPW][DD];   // 8192 B  (25.6 KB total)
    const int lane = threadIdx.x & 63;
    const int wv   = threadIdx.x >> 6;
    const int sub  = lane >> 4;
    const int m    = lane & 15;

    stage_wt(W, sWt, threadIdx.x);
    __syncthreads();

    const float bv = bias[lane];
    const float4* hpv  = (const float4*)tsin;
    const float4* wcol = (const float4*)(sWt + lane * WPAD);

    int base = (blockIdx.x * 4 + wv) * NPW;   // 3125 blocks * 32 = 100000 exact

    // ---- gather phase: strictly serial (register-pressure guard) ----
    float dvs[NPW];
#pragma unroll 1
    for (int r = 0; r < NPW; ++r) {
        int n = base + r;
        int c = cnt[n]; if (c > 63) c = 63;
        dvs[r] = rsqrtf((float)cnt[n] + 1.0f);
        float4 s = gather_node(hpv, csr + (size_t)n * CAP, n, c, sub, m);
        if (sub == 0) ((float4*)abuf[wv][r])[m] = s;   // agg row -> wave slot
    }

    // ---- batched matmul: each W b128 read serves NPW nodes ----
    float o[NPW];
#pragma unroll
    for (int r = 0; r < NPW; ++r) o[r] = 0.f;
#pragma unroll
    for (int kk = 0; kk < DD / 4; ++kk) {
        float4 w = wcol[kk];   // b128 column read, conflict-cheap via WPAD
#pragma unroll
        for (int r = 0; r < NPW; ++r) {
            float4 q = ((const float4*)abuf[wv][r])[kk];  // uniform broadcast
            o[r] = fmaf(q.x, w.x, fmaf(q.y, w.y,
                    fmaf(q.z, w.z, fmaf(q.w, w.w, o[r]))));
        }
    }

    // ---- epilogue ----
#pragma unroll
    for (int r = 0; r < NPW; ++r) {
        int n = base + r;
        float t = fmaxf(fmaf(dvs[r], o[r], bv), 0.f);
        float dvout = scale_out ? dvs[r] : 1.0f;
        outp[(size_t)n * DD + lane] = t * dvout;
    }
}

// ---------------------------------------------------------------------------
// Dense FFN (no gather): u = relu(t3@Wf1 + bf1); out = u@Wf2 + bf2.
// Wf1 in LDS (b128 columns); Wf2 in 16 VGPRs/lane. (Unchanged this round.)
// ---------------------------------------------------------------------------
__global__ __launch_bounds__(256, 4) void k_ffn(const float* __restrict__ t3,
                                                const float* __restrict__ Wf1,
                                                const float* __restrict__ bf1,
                                                const float* __restrict__ Wf2,
                                                const float* __restrict__ bf2,
                                                float* __restrict__ out) {
    __shared__ float sW1t[DD * WPAD];    // 17408 B
    __shared__ float tbuf[4][DD];        // 1024 B (t rows, then u rows)
    const int lane = threadIdx.x & 63;
    const int wv   = threadIdx.x >> 6;
    const int sub  = lane >> 4;   // K-quarter for the 2nd matmul
    const int m    = lane & 15;

    stage_wt(Wf1, sW1t, threadIdx.x);
    __syncthreads();

    float W2reg[16];
#pragma unroll
    for (int kk = 0; kk < 16; ++kk) W2reg[kk] = Wf2[(sub * 16 + kk) * DOUT + m];
    const float b1v = bf1[lane];
    const float b2v = bf2[m];
    const float4* w1col = (const float4*)(sW1t + lane * WPAD);

    int base = (blockIdx.x * 4 + wv) * NPW;
    for (int r = 0; r < NPW; ++r) {
        int n = base + r;
        if (n >= NN) return;
        tbuf[wv][lane] = t3[(size_t)n * DD + lane];  // coalesced row load
        const float4* tb = (const float4*)tbuf[wv];
        float u = b1v;
#pragma unroll
        for (int kk = 0; kk < DD / 4; ++kk) {
            float4 w = w1col[kk];
            float4 q = tb[kk];
            u = fmaf(q.x, w.x, fmaf(q.y, w.y, fmaf(q.z, w.z, fmaf(q.w, w.w, u))));
        }
        u = fmaxf(u, 0.f);

        tbuf[wv][lane] = u;   // overwrite (wave-private; lgkmcnt orders RAW)
        const float4* ub = (const float4*)(tbuf[wv] + sub * 16);
        float p = 0.f;
#pragma unroll
        for (int kq = 0; kq < 4; ++kq) {
            float4 z = ub[kq];
            p = fmaf(z.x, W2reg[4 * kq + 0],
                fmaf(z.y, W2reg[4 * kq + 1],
                fmaf(z.z, W2reg[4 * kq + 2],
                fmaf(z.w, W2reg[4 * kq + 3], p))));
        }
        p += __shfl_xor(p, 16);
        p += __shfl_xor(p, 32);
        if (lane < 16) out[(size_t)n * DOUT + m] = p + b2v;
    }
}

// ---------------------------------------------------------------------------
extern "C" void kernel_launch(void* const* d_in, const int* in_sizes, int n_in,
                              void* d_out, int out_size, void* d_ws, size_t ws_size,
                              hipStream_t stream) {
    const float* x   = (const float*)d_in[0];
    const int*   ei  = (const int*)d_in[1];
    const float* W1  = (const float*)d_in[2];
    const float* b1  = (const float*)d_in[3];
    const float* W2  = (const float*)d_in[4];
    const float* b2  = (const float*)d_in[5];
    const float* W3  = (const float*)d_in[6];
    const float* b3  = (const float*)d_in[7];
    const float* Wf1 = (const float*)d_in[8];
    const float* bf1 = (const float*)d_in[9];
    const float* Wf2 = (const float*)d_in[10];
    const float* bf2 = (const float*)d_in[11];
    float* out = (float*)d_out;

    char* ws = (char*)d_ws;
    auto al = [](size_t v) { return (v + 255) & ~(size_t)255; };
    size_t off = 0;
    int*   cnt  = (int*)(ws + off);   off = al(off + (size_t)NN * 4);
    int*   gcur = (int*)(ws + off);   off = al(off + (size_t)NB * 4);
    int*   csr  = (int*)(ws + off);   off = al(off + (size_t)NN * CAP * 4);
    float* A    = (float*)(ws + off); off = al(off + (size_t)(NN + 1) * DD * 4);
    float* B    = (float*)(ws + off); off = al(off + (size_t)(NN + 1) * DD * 4);

    // Lifetime-disjoint alias: bed (196*10240 int2 = 16.06 MB) in A's first
    // 16.1 MB — consumed by k_csr, then A is overwritten by k_scale.
    int2* bed = (int2*)A;

    hipMemsetAsync(cnt, 0, (size_t)NN * 4, stream);
    hipMemsetAsync(gcur, 0, (size_t)NB * 4, stream);
    hipMemsetAsync(A + (size_t)NN * DD, 0, DD * 4, stream);  // zero sentinel rows
    hipMemsetAsync(B + (size_t)NN * DD, 0, DD * 4, stream);

    k_scatter2<<<NBL, 256, 0, stream>>>(ei, gcur, bed);
    k_csr<<<NB, 1024, 0, stream>>>(bed, gcur, cnt, csr);

    int gf = NN / (4 * NPW);                       // 3125 blocks, exact cover

    // ts0 = x * dinv -> A   (overwrites bed)
    k_scale<<<(NN * (DD / 4) + 255) / 256, 256, 0, stream>>>(x, cnt, A);
    // layer 1: ts1 = relu(dinv*(agg(ts0)@W1)+b1)*dinv -> B
    k_layer<<<gf, 256, 0, stream>>>(A, csr, cnt, b1, W1, 1, B);
    // layer 2: ts2 -> A
    k_layer<<<gf, 256, 0, stream>>>(B, csr, cnt, b2, W2, 1, A);
    // layer 3: t3 (UNSCALED, feeds FFN) -> B
    k_layer<<<gf, 256, 0, stream>>>(A, csr, cnt, b3, W3, 0, B);
    // FFN: out = relu(t3@Wf1+bf1)@Wf2 + bf2
    k_ffn<<<gf, 256, 0, stream>>>(B, Wf1, bf1, Wf2, bf2, out);
}

// Round 14
// 404.393 us; speedup vs baseline: 3.0135x; 1.0540x over previous
//
#include <hip/hip_runtime.h>

#define NN   100000   // nodes
#define EE   1600000  // edges
#define DD   64       // feature dim
#define DOUT 16       // output dim
#define CAP  64       // CSR slots per node (1 self + 63 edges; P(deg>63) ~ 1e-19)
#define NPW  8        // nodes per wave (gathers strictly serial)
#define WPAD 68       // padded W row stride in words (multiple of 4: b128 16B-aligned)

// --- build params ---
#define BSH  9                         // bucket = dst >> 9 (512 nodes/bucket)
#define NB   196                       // ceil(100000 / 512)
#define BCAP 10240                     // slots per bucket (Poisson(8192) + 22 sigma)
#define EPB  2048                      // edges per scatter block
#define NBL  ((EE + EPB - 1) / EPB)    // 782 scatter blocks

// ---------------------------------------------------------------------------
// Build K1: one-pass binning scatter. Per block: LDS histogram of its 2048
// edges -> ONE global atomicAdd per (block,bucket) reserves a range in the
// bucket's fixed BCAP region -> LDS cursors -> write int2(src,dst).
// Block 0 also zeroes the two sentinel rows (consumed much later by k_layer).
// ---------------------------------------------------------------------------
__global__ __launch_bounds__(256) void k_scatter2(const int* __restrict__ ei,
                                                  int* __restrict__ gcur,
                                                  int2* __restrict__ bed,
                                                  float* __restrict__ As,
                                                  float* __restrict__ Bs) {
    if (blockIdx.x == 0) {
        int t = threadIdx.x;
        if (t < DD) As[(size_t)NN * DD + t] = 0.f;
        else if (t < 2 * DD) Bs[(size_t)NN * DD + (t - DD)] = 0.f;
    }
    __shared__ int h[NB];
    __shared__ int cur[NB];
    for (int i = threadIdx.x; i < NB; i += 256) h[i] = 0;
    __syncthreads();
    int e0 = blockIdx.x * EPB;
    int e1 = min(e0 + EPB, EE);
    for (int e = e0 + (int)threadIdx.x; e < e1; e += 256)
        atomicAdd(&h[ei[EE + e] >> BSH], 1);
    __syncthreads();
    for (int i = threadIdx.x; i < NB; i += 256)
        cur[i] = i * BCAP + (h[i] ? atomicAdd(&gcur[i], h[i]) : 0);
    __syncthreads();
    for (int e = e0 + (int)threadIdx.x; e < e1; e += 256) {
        int s = ei[e], d = ei[EE + e];
        int b = d >> BSH;
        int p = atomicAdd(&cur[b], 1);
        if (p < (b + 1) * BCAP) bed[p] = make_int2(s, d);  // 22-sigma guard
    }
}

// ---------------------------------------------------------------------------
// Build K2 + fused scale: one 1024-thread block per bucket.
// (a) CSR build with LDS atomics on the bucket's 512-entry count slice
//     (bucket region holds ALL edges with dst in the bucket, so counts are
//     block-final); (b) write cnt slice; (c) ts0 = x * rsqrt(cnt+1) for the
//     bucket's 512 nodes (deletes the separate k_scale kernel; linearity:
//     agg((t@W)*dinv) == agg(t*dinv) @ W, stored rows are always t*dinv).
// ---------------------------------------------------------------------------
__global__ __launch_bounds__(1024) void k_csr(const int2* __restrict__ bed,
                                              const int* __restrict__ gcur,
                                              const float* __restrict__ x,
                                              int* __restrict__ cnt,
                                              int* __restrict__ csr,
                                              float* __restrict__ ts0) {
    __shared__ int lcnt[512];
    int b     = blockIdx.x;
    int nbase = b << BSH;
    int nmax  = min(512, NN - nbase);
    for (int i = threadIdx.x; i < 512; i += 1024) lcnt[i] = 0;
    __syncthreads();
    int lo = b * BCAP;
    int hi = lo + min(gcur[b], BCAP);
    for (int e = lo + (int)threadIdx.x; e < hi; e += 1024) {
        int2 sd = bed[e];
        int pos = atomicAdd(&lcnt[sd.y - nbase], 1);   // LDS atomic
        if (pos < CAP) csr[(size_t)sd.y * CAP + pos] = sd.x;
    }
    __syncthreads();
    for (int i = threadIdx.x; i < nmax; i += 1024)
        cnt[nbase + i] = lcnt[i];
    const float4* xv = (const float4*)x;
    float4*       ov = (float4*)ts0;
    for (int idx = threadIdx.x; idx < nmax * 16; idx += 1024) {
        float dv = rsqrtf((float)lcnt[idx >> 4] + 1.0f);
        float4 v = xv[(size_t)nbase * 16 + idx];
        v.x *= dv; v.y *= dv; v.z *= dv; v.w *= dv;
        ov[(size_t)nbase * 16 + idx] = v;
    }
}

// ---------------------------------------------------------------------------
// Gather one node's aggregated row (features 4m..4m+3, replicated in all
// lanes after the xor-reduce). Row indices: direct global b32 loads (VMEM
// pipe). One branchless round of 8 dwordx4 covers deg<=31; rare wave-uniform
// 2nd round covers deg<=63. Row NN is a zero sentinel. Needs ~52 free VGPRs
// to keep all 8 loads in flight:
//   - round 6/9: batching GATHERS across nodes -> 256 VGPR -> spills
//   - round 10: (512,8) budget 64 -> 32 VGPR -> 1.3 GB spill traffic
//   - round 11: (256,8) budget 64 -> 32 VGPR, loads serialized, no net win
// Proven operating point: __launch_bounds__(256,4), serial per-node calls.
// r13 note: k_layer is NOT LDS-bound — batched-W matmul was neutral; the
// ~76 us/layer plateau is VMEM latency + cross-XCD L2 misses (189 MB/layer).
// ---------------------------------------------------------------------------
__device__ __forceinline__ float4 gather_node(const float4* __restrict__ hpv,
                                              const int* __restrict__ crow,
                                              int n, int c, int sub, int m) {
    float4 fa = {0.f, 0.f, 0.f, 0.f}, fb = fa;
#define GROW(g, acc)                                                        \
    {                                                                       \
        int idx = 4 * (g) + sub;                                            \
        int rv  = crow[idx ? idx - 1 : 0];                                  \
        int row = (idx == 0) ? n : ((idx <= c) ? rv : NN);                  \
        float4 v = hpv[(size_t)row * 16 + m];                               \
        acc.x += v.x; acc.y += v.y; acc.z += v.z; acc.w += v.w;             \
    }
    GROW(0, fa) GROW(1, fb) GROW(2, fa) GROW(3, fb)
    GROW(4, fa) GROW(5, fb) GROW(6, fa) GROW(7, fb)
    if (c >= 32) {  // wave-uniform, P ~ 3e-4
#define GROW2(g, acc)                                                       \
        {                                                                   \
            int idx = 32 + 4 * (g) + sub;                                   \
            int rv  = crow[idx - 1];                                        \
            int row = (idx <= c) ? rv : NN;                                 \
            float4 v = hpv[(size_t)row * 16 + m];                           \
            acc.x += v.x; acc.y += v.y; acc.z += v.z; acc.w += v.w;         \
        }
        GROW2(0, fa) GROW2(1, fb) GROW2(2, fa) GROW2(3, fb)
        GROW2(4, fa) GROW2(5, fb) GROW2(6, fa) GROW2(7, fb)
#undef GROW2
    }
#undef GROW
    float4 s;
    s.x = fa.x + fb.x; s.y = fa.y + fb.y; s.z = fa.z + fb.z; s.w = fa.w + fb.w;
    s.x += __shfl_xor(s.x, 16); s.y += __shfl_xor(s.y, 16);
    s.z += __shfl_xor(s.z, 16); s.w += __shfl_xor(s.w, 16);
    s.x += __shfl_xor(s.x, 32); s.y += __shfl_xor(s.y, 32);
    s.z += __shfl_xor(s.z, 32); s.w += __shfl_xor(s.w, 32);
    return s;
}

// ---------------------------------------------------------------------------
// Stage W transposed+padded into LDS: sWt[j*WPAD + k] = W[k*64 + j].
// ---------------------------------------------------------------------------
__device__ __forceinline__ void stage_wt(const float* __restrict__ W,
                                         float* __restrict__ sWt, int tid) {
    for (int i = tid; i < DD * DD; i += 256) {
        int k = i >> 6, j = i & 63;
        sWt[j * WPAD + k] = W[i];   // coalesced global read, once per block
    }
}

// ---------------------------------------------------------------------------
// One GCN layer (used 3x) — round-12 per-node form (measured best; r13's
// batched matmul was neutral since the kernel is VMEM-latency-bound).
// agg = gather(ts_in); t = relu(dinv*(agg@W)+b); out = t*(scale_out?dinv:1).
// LDS 18.4 KB; (256,4) budget 128 keeps the gather's 8 loads in flight.
// ---------------------------------------------------------------------------
__global__ __launch_bounds__(256, 4) void k_layer(const float* __restrict__ tsin,
                                                  const int* __restrict__ csr,
                                                  const int* __restrict__ cnt,
                                                  const float* __restrict__ bias,
                                                  const float* __restrict__ W,
                                                  const int scale_out,
                                                  float* __restrict__ outp) {
    __shared__ float sWt[DD * WPAD];     // 17408 B
    __shared__ float abuf[4][DD];        // 1024 B
    const int lane = threadIdx.x & 63;
    const int wv   = threadIdx.x >> 6;
    const int sub  = lane >> 4;
    const int m    = lane & 15;

    stage_wt(W, sWt, threadIdx.x);
    __syncthreads();

    const float bv = bias[lane];
    const float4* hpv  = (const float4*)tsin;
    const float4* wcol = (const float4*)(sWt + lane * WPAD);

    int base = (blockIdx.x * 4 + wv) * NPW;   // 3125 blocks * 32 = 100000 exact
    for (int r = 0; r < NPW; ++r) {
        int n = base + r;
        if (n >= NN) return;
        int c = cnt[n]; if (c > 63) c = 63;
        float dv = rsqrtf((float)cnt[n] + 1.0f);
        float4 s = gather_node(hpv, csr + (size_t)n * CAP, n, c, sub, m);
        if (sub == 0) ((float4*)abuf[wv])[m] = s;   // agg row -> wave slot

        const float4* ab = (const float4*)abuf[wv];
        float o = 0.f;
#pragma unroll
        for (int kk = 0; kk < DD / 4; ++kk) {
            float4 w = wcol[kk];   // b128 column read, conflict-cheap via WPAD
            float4 q = ab[kk];     // wave-uniform -> LDS broadcast
            o = fmaf(q.x, w.x, fmaf(q.y, w.y, fmaf(q.z, w.z, fmaf(q.w, w.w, o))));
        }
        float t = fmaxf(fmaf(dv, o, bv), 0.f);
        float dvout = scale_out ? dv : 1.0f;   // wave-uniform cndmask
        outp[(size_t)n * DD + lane] = t * dvout;
    }
}

// ---------------------------------------------------------------------------
// Dense FFN, BATCHED (no gather -> none of the gather register hazards):
// stage 8 t-rows in wave-private LDS, then each Wf1 b128 read serves 8 nodes
// (16 -> 2 W-reads/node; this kernel IS LDS-bound: ~280 cyc/node before).
// u = relu(t3@Wf1 + bf1) rows overwrite the stage; out = u@Wf2 + bf2 with
// Wf2 in 16 VGPRs/lane, quarter-K per sub + 2 xor-reduces.
// ---------------------------------------------------------------------------
__global__ __launch_bounds__(256, 4) void k_ffn(const float* __restrict__ t3,
                                                const float* __restrict__ Wf1,
                                                const float* __restrict__ bf1,
                                                const float* __restrict__ Wf2,
                                                const float* __restrict__ bf2,
                                                float* __restrict__ out) {
    __shared__ float sW1t[DD * WPAD];    // 17408 B
    __shared__ float tb8[4][NPW][DD];    // 8192 B (t rows, then u rows)
    const int lane = threadIdx.x & 63;
    const int wv   = threadIdx.x >> 6;
    const int sub  = lane >> 4;   // K-quarter for the 2nd matmul
    const int m    = lane & 15;

    stage_wt(Wf1, sW1t, threadIdx.x);
    __syncthreads();

    float W2reg[16];
#pragma unroll
    for (int kk = 0; kk < 16; ++kk) W2reg[kk] = Wf2[(sub * 16 + kk) * DOUT + m];
    const float b1v = bf1[lane];
    const float b2v = bf2[m];
    const float4* w1col = (const float4*)(sW1t + lane * WPAD);

    int base = (blockIdx.x * 4 + wv) * NPW;   // exact cover

    // ---- stage 8 t rows (8 independent coalesced loads -> good MLP) ----
#pragma unroll
    for (int r = 0; r < NPW; ++r)
        tb8[wv][r][lane] = t3[(size_t)(base + r) * DD + lane];

    // ---- batched matmul1: u = relu(t @ Wf1 + bf1) ----
    float u[NPW];
#pragma unroll
    for (int r = 0; r < NPW; ++r) u[r] = b1v;
#pragma unroll
    for (int kk = 0; kk < DD / 4; ++kk) {
        float4 w = w1col[kk];
#pragma unroll
        for (int r = 0; r < NPW; ++r) {
            float4 q = ((const float4*)tb8[wv][r])[kk];  // uniform broadcast
            u[r] = fmaf(q.x, w.x, fmaf(q.y, w.y,
                    fmaf(q.z, w.z, fmaf(q.w, w.w, u[r]))));
        }
    }
#pragma unroll
    for (int r = 0; r < NPW; ++r)
        tb8[wv][r][lane] = fmaxf(u[r], 0.f);   // u rows overwrite t rows

    // ---- batched matmul2: out = u @ Wf2 + bf2 ----
    float p[NPW];
#pragma unroll
    for (int r = 0; r < NPW; ++r) p[r] = 0.f;
#pragma unroll
    for (int kq = 0; kq < 4; ++kq) {
        float a0 = W2reg[4 * kq + 0], a1 = W2reg[4 * kq + 1];
        float a2 = W2reg[4 * kq + 2], a3 = W2reg[4 * kq + 3];
#pragma unroll
        for (int r = 0; r < NPW; ++r) {
            float4 z = ((const float4*)(tb8[wv][r] + sub * 16))[kq];
            p[r] = fmaf(z.x, a0, fmaf(z.y, a1, fmaf(z.z, a2, fmaf(z.w, a3, p[r]))));
        }
    }
#pragma unroll
    for (int r = 0; r < NPW; ++r) {
        p[r] += __shfl_xor(p[r], 16);
        p[r] += __shfl_xor(p[r], 32);
        if (lane < 16) out[(size_t)(base + r) * DOUT + m] = p[r] + b2v;
    }
}

// ---------------------------------------------------------------------------
extern "C" void kernel_launch(void* const* d_in, const int* in_sizes, int n_in,
                              void* d_out, int out_size, void* d_ws, size_t ws_size,
                              hipStream_t stream) {
    const float* x   = (const float*)d_in[0];
    const int*   ei  = (const int*)d_in[1];
    const float* W1  = (const float*)d_in[2];
    const float* b1  = (const float*)d_in[3];
    const float* W2  = (const float*)d_in[4];
    const float* b2  = (const float*)d_in[5];
    const float* W3  = (const float*)d_in[6];
    const float* b3  = (const float*)d_in[7];
    const float* Wf1 = (const float*)d_in[8];
    const float* bf1 = (const float*)d_in[9];
    const float* Wf2 = (const float*)d_in[10];
    const float* bf2 = (const float*)d_in[11];
    float* out = (float*)d_out;

    char* ws = (char*)d_ws;
    auto al = [](size_t v) { return (v + 255) & ~(size_t)255; };
    size_t off = 0;
    int*   cnt  = (int*)(ws + off);   off = al(off + (size_t)NN * 4);
    int*   gcur = (int*)(ws + off);   off = al(off + (size_t)NB * 4);
    int*   csr  = (int*)(ws + off);   off = al(off + (size_t)NN * CAP * 4);
    float* A    = (float*)(ws + off); off = al(off + (size_t)(NN + 1) * DD * 4);
    float* B    = (float*)(ws + off); off = al(off + (size_t)(NN + 1) * DD * 4);

    // Lifetime-disjoint alias: bed (196*10240 int2 = 16.06 MB) lives in B's
    // first 16.1 MB. k_csr consumes bed while writing ts0 into A (disjoint
    // buffers); layer 1 then overwrites B. B's sentinel row (at 25.6 MB) is
    // beyond the alias.
    int2* bed = (int2*)B;

    hipMemsetAsync(gcur, 0, (size_t)NB * 4, stream);
    k_scatter2<<<NBL, 256, 0, stream>>>(ei, gcur, bed, A, B);
    // CSR (LDS atomics) + fused ts0 = x*dinv -> A
    k_csr<<<NB, 1024, 0, stream>>>(bed, gcur, x, cnt, csr, A);

    int gf = NN / (4 * NPW);                       // 3125 blocks, exact cover

    // layer 1: ts1 = relu(dinv*(agg(ts0)@W1)+b1)*dinv -> B  (overwrites bed)
    k_layer<<<gf, 256, 0, stream>>>(A, csr, cnt, b1, W1, 1, B);
    // layer 2: ts2 -> A
    k_layer<<<gf, 256, 0, stream>>>(B, csr, cnt, b2, W2, 1, A);
    // layer 3: t3 (UNSCALED, feeds FFN) -> B
    k_layer<<<gf, 256, 0, stream>>>(A, csr, cnt, b3, W3, 0, B);
    // FFN: out = relu(t3@Wf1+bf1)@Wf2 + bf2
    k_ffn<<<gf, 256, 0, stream>>>(B, Wf1, bf1, Wf2, bf2, out);
}

// Round 15
// 344.437 us; speedup vs baseline: 3.5380x; 1.1741x over previous
//
#include <hip/hip_runtime.h>

#define NN   100000   // nodes
#define EE   1600000  // edges
#define DD   64       // feature dim
#define DOUT 16       // output dim
#define CAP  64       // CSR slots per node (1 self + 63 edges; P(deg>63) ~ 1e-19)
#define NPW  8        // nodes per wave (gathers strictly serial)
#define WPAD 68       // padded W row stride in words (multiple of 4: b128 16B-aligned)

// --- build params ---
#define BSH  9                         // bucket = dst >> 9 (512 nodes/bucket)
#define NB   196                       // ceil(100000 / 512)
#define BCAP 10240                     // slots per bucket (Poisson(8192) + 22 sigma)
#define EPB  2048                      // edges per scatter block
#define NBL  ((EE + EPB - 1) / EPB)    // 782 scatter blocks

// --- bf16 helpers (features stored bf16; ALL arithmetic fp32) ---
__device__ __forceinline__ float lo16(unsigned u) {
    union { unsigned i; float f; } v; v.i = u << 16; return v.f;
}
__device__ __forceinline__ float hi16(unsigned u) {
    union { unsigned i; float f; } v; v.i = u & 0xffff0000u; return v.f;
}
__device__ __forceinline__ unsigned short f2bf(float f) {   // RNE
    union { float f; unsigned i; } v; v.f = f;
    return (unsigned short)((v.i + 0x7fffu + ((v.i >> 16) & 1u)) >> 16);
}

// ---------------------------------------------------------------------------
// Build K1: one-pass binning scatter (LDS hist -> one global atomicAdd per
// (block,bucket) -> LDS cursors -> int2 writes). Block 0 zeroes the bf16
// sentinel rows (row NN of A and B, 128 B each).
// ---------------------------------------------------------------------------
__global__ __launch_bounds__(256) void k_scatter2(const int* __restrict__ ei,
                                                  int* __restrict__ gcur,
                                                  int2* __restrict__ bed,
                                                  unsigned* __restrict__ As,
                                                  unsigned* __restrict__ Bs) {
    if (blockIdx.x == 0) {
        int t = threadIdx.x;
        if (t < 32) As[(size_t)NN * 32 + t] = 0u;
        else if (t < 64) Bs[(size_t)NN * 32 + (t - 32)] = 0u;
    }
    __shared__ int h[NB];
    __shared__ int cur[NB];
    for (int i = threadIdx.x; i < NB; i += 256) h[i] = 0;
    __syncthreads();
    int e0 = blockIdx.x * EPB;
    int e1 = min(e0 + EPB, EE);
    for (int e = e0 + (int)threadIdx.x; e < e1; e += 256)
        atomicAdd(&h[ei[EE + e] >> BSH], 1);
    __syncthreads();
    for (int i = threadIdx.x; i < NB; i += 256)
        cur[i] = i * BCAP + (h[i] ? atomicAdd(&gcur[i], h[i]) : 0);
    __syncthreads();
    for (int e = e0 + (int)threadIdx.x; e < e1; e += 256) {
        int s = ei[e], d = ei[EE + e];
        int b = d >> BSH;
        int p = atomicAdd(&cur[b], 1);
        if (p < (b + 1) * BCAP) bed[p] = make_int2(s, d);  // 22-sigma guard
    }
}

// ---------------------------------------------------------------------------
// Build K2 + fused scale: one 1024-thread block per bucket. CSR via LDS
// atomics on the bucket's 512-entry count slice; then ts0 = bf16(x * dinv)
// for the bucket's nodes (packed uint stores).
// ---------------------------------------------------------------------------
__global__ __launch_bounds__(1024) void k_csr(const int2* __restrict__ bed,
                                              const int* __restrict__ gcur,
                                              const float* __restrict__ x,
                                              int* __restrict__ cnt,
                                              int* __restrict__ csr,
                                              unsigned* __restrict__ ts0) {
    __shared__ int lcnt[512];
    int b     = blockIdx.x;
    int nbase = b << BSH;
    int nmax  = min(512, NN - nbase);
    for (int i = threadIdx.x; i < 512; i += 1024) lcnt[i] = 0;
    __syncthreads();
    int lo = b * BCAP;
    int hi = lo + min(gcur[b], BCAP);
    for (int e = lo + (int)threadIdx.x; e < hi; e += 1024) {
        int2 sd = bed[e];
        int pos = atomicAdd(&lcnt[sd.y - nbase], 1);   // LDS atomic
        if (pos < CAP) csr[(size_t)sd.y * CAP + pos] = sd.x;
    }
    __syncthreads();
    for (int i = threadIdx.x; i < nmax; i += 1024)
        cnt[nbase + i] = lcnt[i];
    const float2* xv = (const float2*)x;
    for (int idx = threadIdx.x; idx < nmax * 32; idx += 1024) {  // packed uints
        float dv = rsqrtf((float)lcnt[idx >> 5] + 1.0f);
        float2 v = xv[(size_t)nbase * 32 + idx];
        ts0[(size_t)nbase * 32 + idx] =
            (unsigned)f2bf(v.x * dv) | ((unsigned)f2bf(v.y * dv) << 16);
    }
}

// ---------------------------------------------------------------------------
// Gather one node's aggregated row from bf16 rows (128 B/row; lane m loads
// uint2 = feats 4m..4m+3), fp32 accumulate, xor-reduce -> float4 all lanes.
// Indices via direct global b32 loads (VMEM). 8 dwordx2 in flight covers
// deg<=31; rare wave-uniform 2nd round covers deg<=63. Row NN zero sentinel.
// Register discipline unchanged (r6/r9/r10/r11 lessons): serial per-node
// calls, (256,4) budget. bf16 halves in-flight bytes -> pressure DROPS.
// r13/r15 note: k_layer is VMEM-side bound (189 MB L2-miss/layer @ fp32);
// bf16 is the byte-halving experiment.
// ---------------------------------------------------------------------------
__device__ __forceinline__ float4 gather_node(const uint2* __restrict__ hpv,
                                              const int* __restrict__ crow,
                                              int n, int c, int sub, int m) {
    float4 fa = {0.f, 0.f, 0.f, 0.f}, fb = fa;
#define GROW(g, acc)                                                        \
    {                                                                       \
        int idx = 4 * (g) + sub;                                            \
        int rv  = crow[idx ? idx - 1 : 0];                                  \
        int row = (idx == 0) ? n : ((idx <= c) ? rv : NN);                  \
        uint2 U = hpv[(size_t)row * 16 + m];                                \
        acc.x += lo16(U.x); acc.y += hi16(U.x);                             \
        acc.z += lo16(U.y); acc.w += hi16(U.y);                             \
    }
    GROW(0, fa) GROW(1, fb) GROW(2, fa) GROW(3, fb)
    GROW(4, fa) GROW(5, fb) GROW(6, fa) GROW(7, fb)
    if (c >= 32) {  // wave-uniform, P ~ 3e-4
#define GROW2(g, acc)                                                       \
        {                                                                   \
            int idx = 32 + 4 * (g) + sub;                                   \
            int rv  = crow[idx - 1];                                        \
            int row = (idx <= c) ? rv : NN;                                 \
            uint2 U = hpv[(size_t)row * 16 + m];                            \
            acc.x += lo16(U.x); acc.y += hi16(U.x);                         \
            acc.z += lo16(U.y); acc.w += hi16(U.y);                         \
        }
        GROW2(0, fa) GROW2(1, fb) GROW2(2, fa) GROW2(3, fb)
        GROW2(4, fa) GROW2(5, fb) GROW2(6, fa) GROW2(7, fb)
#undef GROW2
    }
#undef GROW
    float4 s;
    s.x = fa.x + fb.x; s.y = fa.y + fb.y; s.z = fa.z + fb.z; s.w = fa.w + fb.w;
    s.x += __shfl_xor(s.x, 16); s.y += __shfl_xor(s.y, 16);
    s.z += __shfl_xor(s.z, 16); s.w += __shfl_xor(s.w, 16);
    s.x += __shfl_xor(s.x, 32); s.y += __shfl_xor(s.y, 32);
    s.z += __shfl_xor(s.z, 32); s.w += __shfl_xor(s.w, 32);
    return s;
}

// ---------------------------------------------------------------------------
// Stage W transposed+padded into LDS: sWt[j*WPAD + k] = W[k*64 + j].
// ---------------------------------------------------------------------------
__device__ __forceinline__ void stage_wt(const float* __restrict__ W,
                                         float* __restrict__ sWt, int tid) {
    for (int i = tid; i < DD * DD; i += 256) {
        int k = i >> 6, j = i & 63;
        sWt[j * WPAD + k] = W[i];   // coalesced global read, once per block
    }
}

// ---------------------------------------------------------------------------
// One GCN layer: agg = gather(bf16 ts_in); t = relu(dinv*(agg@W)+b);
// store t*dinv as bf16 (OUTBF=1) or t as fp32 (OUTBF=0 — layer 3, feeds FFN
// directly so it keeps full precision; removes one of four rounding stages).
// ---------------------------------------------------------------------------
template <int OUTBF>
__global__ __launch_bounds__(256, 4) void k_layer(const unsigned short* __restrict__ tsin,
                                                  const int* __restrict__ csr,
                                                  const int* __restrict__ cnt,
                                                  const float* __restrict__ bias,
                                                  const float* __restrict__ W,
                                                  void* __restrict__ outp) {
    __shared__ float sWt[DD * WPAD];     // 17408 B
    __shared__ float abuf[4][DD];        // 1024 B
    const int lane = threadIdx.x & 63;
    const int wv   = threadIdx.x >> 6;
    const int sub  = lane >> 4;
    const int m    = lane & 15;

    stage_wt(W, sWt, threadIdx.x);
    __syncthreads();

    const float bv = bias[lane];
    const uint2* hpv   = (const uint2*)tsin;
    const float4* wcol = (const float4*)(sWt + lane * WPAD);

    int base = (blockIdx.x * 4 + wv) * NPW;   // 3125 blocks * 32 = 100000 exact
    for (int r = 0; r < NPW; ++r) {
        int n = base + r;
        if (n >= NN) return;
        int c = cnt[n]; if (c > 63) c = 63;
        float dv = rsqrtf((float)cnt[n] + 1.0f);
        float4 s = gather_node(hpv, csr + (size_t)n * CAP, n, c, sub, m);
        if (sub == 0) ((float4*)abuf[wv])[m] = s;   // agg row -> wave slot

        const float4* ab = (const float4*)abuf[wv];
        float o = 0.f;
#pragma unroll
        for (int kk = 0; kk < DD / 4; ++kk) {
            float4 w = wcol[kk];   // b128 column read, conflict-cheap via WPAD
            float4 q = ab[kk];     // wave-uniform -> LDS broadcast
            o = fmaf(q.x, w.x, fmaf(q.y, w.y, fmaf(q.z, w.z, fmaf(q.w, w.w, o))));
        }
        float t = fmaxf(fmaf(dv, o, bv), 0.f);
        if (OUTBF)
            ((unsigned short*)outp)[(size_t)n * DD + lane] = f2bf(t * dv);
        else
            ((float*)outp)[(size_t)n * DD + lane] = t;
    }
}

// ---------------------------------------------------------------------------
// Dense FFN, batched (reads fp32 t3): stage 8 t-rows in wave-private LDS,
// each Wf1 b128 read serves 8 nodes; u rows overwrite the stage;
// out = u@Wf2 + bf2 with Wf2 in 16 VGPRs/lane, quarter-K + 2 xor-reduces.
// ---------------------------------------------------------------------------
__global__ __launch_bounds__(256, 4) void k_ffn(const float* __restrict__ t3,
                                                const float* __restrict__ Wf1,
                                                const float* __restrict__ bf1,
                                                const float* __restrict__ Wf2,
                                                const float* __restrict__ bf2,
                                                float* __restrict__ out) {
    __shared__ float sW1t[DD * WPAD];    // 17408 B
    __shared__ float tb8[4][NPW][DD];    // 8192 B (t rows, then u rows)
    const int lane = threadIdx.x & 63;
    const int wv   = threadIdx.x >> 6;
    const int sub  = lane >> 4;   // K-quarter for the 2nd matmul
    const int m    = lane & 15;

    stage_wt(Wf1, sW1t, threadIdx.x);
    __syncthreads();

    float W2reg[16];
#pragma unroll
    for (int kk = 0; kk < 16; ++kk) W2reg[kk] = Wf2[(sub * 16 + kk) * DOUT + m];
    const float b1v = bf1[lane];
    const float b2v = bf2[m];
    const float4* w1col = (const float4*)(sW1t + lane * WPAD);

    int base = (blockIdx.x * 4 + wv) * NPW;   // exact cover

#pragma unroll
    for (int r = 0; r < NPW; ++r)
        tb8[wv][r][lane] = t3[(size_t)(base + r) * DD + lane];

    float u[NPW];
#pragma unroll
    for (int r = 0; r < NPW; ++r) u[r] = b1v;
#pragma unroll
    for (int kk = 0; kk < DD / 4; ++kk) {
        float4 w = w1col[kk];
#pragma unroll
        for (int r = 0; r < NPW; ++r) {
            float4 q = ((const float4*)tb8[wv][r])[kk];  // uniform broadcast
            u[r] = fmaf(q.x, w.x, fmaf(q.y, w.y,
                    fmaf(q.z, w.z, fmaf(q.w, w.w, u[r]))));
        }
    }
#pragma unroll
    for (int r = 0; r < NPW; ++r)
        tb8[wv][r][lane] = fmaxf(u[r], 0.f);   // u rows overwrite t rows

    float p[NPW];
#pragma unroll
    for (int r = 0; r < NPW; ++r) p[r] = 0.f;
#pragma unroll
    for (int kq = 0; kq < 4; ++kq) {
        float a0 = W2reg[4 * kq + 0], a1 = W2reg[4 * kq + 1];
        float a2 = W2reg[4 * kq + 2], a3 = W2reg[4 * kq + 3];
#pragma unroll
        for (int r = 0; r < NPW; ++r) {
            float4 z = ((const float4*)(tb8[wv][r] + sub * 16))[kq];
            p[r] = fmaf(z.x, a0, fmaf(z.y, a1, fmaf(z.z, a2, fmaf(z.w, a3, p[r]))));
        }
    }
#pragma unroll
    for (int r = 0; r < NPW; ++r) {
        p[r] += __shfl_xor(p[r], 16);
        p[r] += __shfl_xor(p[r], 32);
        if (lane < 16) out[(size_t)(base + r) * DOUT + m] = p[r] + b2v;
    }
}

// ---------------------------------------------------------------------------
extern "C" void kernel_launch(void* const* d_in, const int* in_sizes, int n_in,
                              void* d_out, int out_size, void* d_ws, size_t ws_size,
                              hipStream_t stream) {
    const float* x   = (const float*)d_in[0];
    const int*   ei  = (const int*)d_in[1];
    const float* W1  = (const float*)d_in[2];
    const float* b1  = (const float*)d_in[3];
    const float* W2  = (const float*)d_in[4];
    const float* b2  = (const float*)d_in[5];
    const float* W3  = (const float*)d_in[6];
    const float* b3  = (const float*)d_in[7];
    const float* Wf1 = (const float*)d_in[8];
    const float* bf1 = (const float*)d_in[9];
    const float* Wf2 = (const float*)d_in[10];
    const float* bf2 = (const float*)d_in[11];
    float* out = (float*)d_out;

    char* ws = (char*)d_ws;
    auto al = [](size_t v) { return (v + 255) & ~(size_t)255; };
    size_t off = 0;
    int* cnt  = (int*)(ws + off);              off = al(off + (size_t)NN * 4);
    int* gcur = (int*)(ws + off);              off = al(off + (size_t)NB * 4);
    int* csr  = (int*)(ws + off);              off = al(off + (size_t)NN * CAP * 4);
    unsigned short* A = (unsigned short*)(ws + off); off = al(off + (size_t)(NN + 1) * DD * 2);
    unsigned short* B = (unsigned short*)(ws + off); off = al(off + (size_t)(NN + 1) * DD * 2);
    float* F  = (float*)(ws + off);            off = al(off + (size_t)NN * DD * 4);

    // bed (16.06 MB) aliases F (25.6 MB): consumed by k_csr, then F is
    // overwritten by layer 3's fp32 output. A/B hold bf16 rows (12.8 MB),
    // sentinel rows at index NN.
    int2* bed = (int2*)F;

    hipMemsetAsync(gcur, 0, (size_t)NB * 4, stream);
    k_scatter2<<<NBL, 256, 0, stream>>>(ei, gcur, bed, (unsigned*)A, (unsigned*)B);
    // CSR (LDS atomics) + fused ts0 = bf16(x*dinv) -> A
    k_csr<<<NB, 1024, 0, stream>>>(bed, gcur, x, cnt, csr, (unsigned*)A);

    int gf = NN / (4 * NPW);                       // 3125 blocks, exact cover

    // layer 1: ts1 = bf16(relu(dinv*(agg(ts0)@W1)+b1)*dinv) -> B
    k_layer<1><<<gf, 256, 0, stream>>>(A, csr, cnt, b1, W1, B);
    // layer 2: ts2 -> A
    k_layer<1><<<gf, 256, 0, stream>>>(B, csr, cnt, b2, W2, A);
    // layer 3: t3 fp32 (UNSCALED, feeds FFN at full precision) -> F
    k_layer<0><<<gf, 256, 0, stream>>>(A, csr, cnt, b3, W3, F);
    // FFN: out = relu(t3@Wf1+bf1)@Wf2 + bf2
    k_ffn<<<gf, 256, 0, stream>>>(F, Wf1, bf1, Wf2, bf2, out);
}

// Round 16
// 338.015 us; speedup vs baseline: 3.6052x; 1.0190x over previous
//
#include <hip/hip_runtime.h>

#define NN   100000   // nodes
#define EE   1600000  // edges
#define DD   64       // feature dim
#define DOUT 16       // output dim
#define CAP  64       // CSR slots/node: slot0=self, 1..63 edges, NN-pads to 32/64
#define NPW  8        // nodes per wave (gathers strictly serial)
#define WPAD 68       // padded W row stride in words (multiple of 4: b128 16B-aligned)

// --- build params ---
#define BSH  9                         // bucket = dst >> 9 (512 nodes/bucket)
#define NB   196                       // ceil(100000 / 512)
#define BCAP 10240                     // slots per bucket (Poisson(8192) + 22 sigma)
#define EPB  2048                      // edges per scatter block
#define NBL  ((EE + EPB - 1) / EPB)    // 782 scatter blocks

// --- bf16 helpers (features stored bf16; ALL arithmetic fp32) ---
__device__ __forceinline__ float lo16(unsigned u) {
    union { unsigned i; float f; } v; v.i = u << 16; return v.f;
}
__device__ __forceinline__ float hi16(unsigned u) {
    union { unsigned i; float f; } v; v.i = u & 0xffff0000u; return v.f;
}
__device__ __forceinline__ unsigned short f2bf(float f) {   // RNE
    union { float f; unsigned i; } v; v.f = f;
    return (unsigned short)((v.i + 0x7fffu + ((v.i >> 16) & 1u)) >> 16);
}

// ---------------------------------------------------------------------------
// Build K1: one-pass binning scatter (LDS hist -> one global atomicAdd per
// (block,bucket) -> LDS cursors -> int2 writes). Block 0 zeroes the bf16
// sentinel rows (row NN of A and B, 128 B each).
// ---------------------------------------------------------------------------
__global__ __launch_bounds__(256) void k_scatter2(const int* __restrict__ ei,
                                                  int* __restrict__ gcur,
                                                  int2* __restrict__ bed,
                                                  unsigned* __restrict__ As,
                                                  unsigned* __restrict__ Bs) {
    if (blockIdx.x == 0) {
        int t = threadIdx.x;
        if (t < 32) As[(size_t)NN * 32 + t] = 0u;
        else if (t < 64) Bs[(size_t)NN * 32 + (t - 32)] = 0u;
    }
    __shared__ int h[NB];
    __shared__ int cur[NB];
    for (int i = threadIdx.x; i < NB; i += 256) h[i] = 0;
    __syncthreads();
    int e0 = blockIdx.x * EPB;
    int e1 = min(e0 + EPB, EE);
    for (int e = e0 + (int)threadIdx.x; e < e1; e += 256)
        atomicAdd(&h[ei[EE + e] >> BSH], 1);
    __syncthreads();
    for (int i = threadIdx.x; i < NB; i += 256)
        cur[i] = i * BCAP + (h[i] ? atomicAdd(&gcur[i], h[i]) : 0);
    __syncthreads();
    for (int e = e0 + (int)threadIdx.x; e < e1; e += 256) {
        int s = ei[e], d = ei[EE + e];
        int b = d >> BSH;
        int p = atomicAdd(&cur[b], 1);
        if (p < (b + 1) * BCAP) bed[p] = make_int2(s, d);  // 22-sigma guard
    }
}

// ---------------------------------------------------------------------------
// Build K2 + fused scale: one 1024-thread block per bucket.
// CSR layout per node: slot 0 = self (n), edges at 1..min(c,63), then
// sentinel-NN pads up to 32 slots (or 64 if c>=32) — makes the gather
// completely SELECT-FREE (r15 counters: the idx ternaries were ~96 VALU/node).
// Then ts0 = bf16(x * dinv) for the bucket's nodes.
// ---------------------------------------------------------------------------
__global__ __launch_bounds__(1024) void k_csr(const int2* __restrict__ bed,
                                              const int* __restrict__ gcur,
                                              const float* __restrict__ x,
                                              int* __restrict__ cnt,
                                              int* __restrict__ csr,
                                              unsigned* __restrict__ ts0) {
    __shared__ int lcnt[512];
    int b     = blockIdx.x;
    int nbase = b << BSH;
    int nmax  = min(512, NN - nbase);
    for (int i = threadIdx.x; i < 512; i += 1024) lcnt[i] = 0;
    __syncthreads();
    int lo = b * BCAP;
    int hi = lo + min(gcur[b], BCAP);
    for (int e = lo + (int)threadIdx.x; e < hi; e += 1024) {
        int2 sd = bed[e];
        int pos = atomicAdd(&lcnt[sd.y - nbase], 1);   // LDS atomic
        if (pos < CAP - 1) csr[(size_t)sd.y * CAP + pos + 1] = sd.x;  // slot0=self
    }
    __syncthreads();
    // cnt, self slot, sentinel pads
    for (int i = threadIdx.x; i < nmax; i += 1024) {
        int n = nbase + i;
        int c = lcnt[i];
        cnt[n] = c;
        if (c > 63) c = 63;
        int used = 1 + c;
        int end  = (used <= 32) ? 32 : 64;
        int* row = csr + (size_t)n * CAP;
        row[0] = n;
        for (int s = used; s < end; ++s) row[s] = NN;   // zero-sentinel pads
    }
    const float2* xv = (const float2*)x;
    for (int idx = threadIdx.x; idx < nmax * 32; idx += 1024) {  // packed uints
        float dv = rsqrtf((float)lcnt[idx >> 5] + 1.0f);
        float2 v = xv[(size_t)nbase * 32 + idx];
        ts0[(size_t)nbase * 32 + idx] =
            (unsigned)f2bf(v.x * dv) | ((unsigned)f2bf(v.y * dv) << 16);
    }
}

// ---------------------------------------------------------------------------
// Gather one node's aggregated row from bf16 rows (128 B/row; lane m loads
// uint2 = feats 4m..4m+3), fp32 accumulate, xor-reduce -> float4 all lanes.
// SELECT-FREE: CSR rows are self+edges+sentinel-padded, so round 1 is just
// crow[4g+sub] (8 loads at constant offsets) and 8 row loads; the rare
// (P~3e-4, wave-uniform) 2nd round covers slots 32..63. 32-bit row offsets
// (12.8 MB < 2^31) let the compiler use SGPR-base + voffset addressing.
// Register discipline unchanged (r6/r9/r10/r11): serial per-node calls,
// (256,4) budget, 8 loads in flight.
// ---------------------------------------------------------------------------
__device__ __forceinline__ float4 gather_node(const uint2* __restrict__ hpv,
                                              const int* __restrict__ crow,
                                              int c, int sub, int m) {
    float4 fa = {0.f, 0.f, 0.f, 0.f}, fb = fa;
#define GROW(g, acc)                                                        \
    {                                                                       \
        int row = crow[4 * (g) + sub];                                      \
        uint2 U = hpv[((unsigned)row << 4) + m];                            \
        acc.x += lo16(U.x); acc.y += hi16(U.x);                             \
        acc.z += lo16(U.y); acc.w += hi16(U.y);                             \
    }
    GROW(0, fa) GROW(1, fb) GROW(2, fa) GROW(3, fb)
    GROW(4, fa) GROW(5, fb) GROW(6, fa) GROW(7, fb)
    if (c >= 32) {  // wave-uniform, P ~ 3e-4
#define GROW2(g, acc)                                                       \
        {                                                                   \
            int row = crow[32 + 4 * (g) + sub];                             \
            uint2 U = hpv[((unsigned)row << 4) + m];                        \
            acc.x += lo16(U.x); acc.y += hi16(U.x);                         \
            acc.z += lo16(U.y); acc.w += hi16(U.y);                         \
        }
        GROW2(0, fa) GROW2(1, fb) GROW2(2, fa) GROW2(3, fb)
        GROW2(4, fa) GROW2(5, fb) GROW2(6, fa) GROW2(7, fb)
#undef GROW2
    }
#undef GROW
    float4 s;
    s.x = fa.x + fb.x; s.y = fa.y + fb.y; s.z = fa.z + fb.z; s.w = fa.w + fb.w;
    s.x += __shfl_xor(s.x, 16); s.y += __shfl_xor(s.y, 16);
    s.z += __shfl_xor(s.z, 16); s.w += __shfl_xor(s.w, 16);
    s.x += __shfl_xor(s.x, 32); s.y += __shfl_xor(s.y, 32);
    s.z += __shfl_xor(s.z, 32); s.w += __shfl_xor(s.w, 32);
    return s;
}

// ---------------------------------------------------------------------------
// Stage W transposed+padded into LDS: sWt[j*WPAD + k] = W[k*64 + j].
// ---------------------------------------------------------------------------
__device__ __forceinline__ void stage_wt(const float* __restrict__ W,
                                         float* __restrict__ sWt, int tid) {
    for (int i = tid; i < DD * DD; i += 256) {
        int k = i >> 6, j = i & 63;
        sWt[j * WPAD + k] = W[i];   // coalesced global read, once per block
    }
}

// ---------------------------------------------------------------------------
// One GCN layer: agg = gather(bf16 ts_in); t = relu(dinv*(agg@W)+b);
// store t*dinv as bf16 (OUTBF=1) or t as fp32 (OUTBF=0 — layer 3, feeds FFN
// directly at full precision).
// ---------------------------------------------------------------------------
template <int OUTBF>
__global__ __launch_bounds__(256, 4) void k_layer(const unsigned short* __restrict__ tsin,
                                                  const int* __restrict__ csr,
                                                  const int* __restrict__ cnt,
                                                  const float* __restrict__ bias,
                                                  const float* __restrict__ W,
                                                  void* __restrict__ outp) {
    __shared__ float sWt[DD * WPAD];     // 17408 B
    __shared__ float abuf[4][DD];        // 1024 B
    const int lane = threadIdx.x & 63;
    const int wv   = threadIdx.x >> 6;
    const int sub  = lane >> 4;
    const int m    = lane & 15;

    stage_wt(W, sWt, threadIdx.x);
    __syncthreads();

    const float bv = bias[lane];
    const uint2* hpv   = (const uint2*)tsin;
    const float4* wcol = (const float4*)(sWt + lane * WPAD);

    int base = (blockIdx.x * 4 + wv) * NPW;   // 3125 blocks * 32 = 100000 exact
    for (int r = 0; r < NPW; ++r) {
        int n = base + r;
        if (n >= NN) return;
        int c = cnt[n]; if (c > 63) c = 63;
        float dv = rsqrtf((float)cnt[n] + 1.0f);
        float4 s = gather_node(hpv, csr + (size_t)n * CAP, c, sub, m);
        if (sub == 0) ((float4*)abuf[wv])[m] = s;   // agg row -> wave slot

        const float4* ab = (const float4*)abuf[wv];
        float o = 0.f;
#pragma unroll
        for (int kk = 0; kk < DD / 4; ++kk) {
            float4 w = wcol[kk];   // b128 column read, conflict-cheap via WPAD
            float4 q = ab[kk];     // wave-uniform -> LDS broadcast
            o = fmaf(q.x, w.x, fmaf(q.y, w.y, fmaf(q.z, w.z, fmaf(q.w, w.w, o))));
        }
        float t = fmaxf(fmaf(dv, o, bv), 0.f);
        if (OUTBF)
            ((unsigned short*)outp)[(size_t)n * DD + lane] = f2bf(t * dv);
        else
            ((float*)outp)[(size_t)n * DD + lane] = t;
    }
}

// ---------------------------------------------------------------------------
// Dense FFN, batched (reads fp32 t3): stage 8 t-rows in wave-private LDS,
// each Wf1 b128 read serves 8 nodes; u rows overwrite the stage;
// out = u@Wf2 + bf2 with Wf2 in 16 VGPRs/lane, quarter-K + 2 xor-reduces.
// ---------------------------------------------------------------------------
__global__ __launch_bounds__(256, 4) void k_ffn(const float* __restrict__ t3,
                                                const float* __restrict__ Wf1,
                                                const float* __restrict__ bf1,
                                                const float* __restrict__ Wf2,
                                                const float* __restrict__ bf2,
                                                float* __restrict__ out) {
    __shared__ float sW1t[DD * WPAD];    // 17408 B
    __shared__ float tb8[4][NPW][DD];    // 8192 B (t rows, then u rows)
    const int lane = threadIdx.x & 63;
    const int wv   = threadIdx.x >> 6;
    const int sub  = lane >> 4;   // K-quarter for the 2nd matmul
    const int m    = lane & 15;

    stage_wt(Wf1, sW1t, threadIdx.x);
    __syncthreads();

    float W2reg[16];
#pragma unroll
    for (int kk = 0; kk < 16; ++kk) W2reg[kk] = Wf2[(sub * 16 + kk) * DOUT + m];
    const float b1v = bf1[lane];
    const float b2v = bf2[m];
    const float4* w1col = (const float4*)(sW1t + lane * WPAD);

    int base = (blockIdx.x * 4 + wv) * NPW;   // exact cover

#pragma unroll
    for (int r = 0; r < NPW; ++r)
        tb8[wv][r][lane] = t3[(size_t)(base + r) * DD + lane];

    float u[NPW];
#pragma unroll
    for (int r = 0; r < NPW; ++r) u[r] = b1v;
#pragma unroll
    for (int kk = 0; kk < DD / 4; ++kk) {
        float4 w = w1col[kk];
#pragma unroll
        for (int r = 0; r < NPW; ++r) {
            float4 q = ((const float4*)tb8[wv][r])[kk];  // uniform broadcast
            u[r] = fmaf(q.x, w.x, fmaf(q.y, w.y,
                    fmaf(q.z, w.z, fmaf(q.w, w.w, u[r]))));
        }
    }
#pragma unroll
    for (int r = 0; r < NPW; ++r)
        tb8[wv][r][lane] = fmaxf(u[r], 0.f);   // u rows overwrite t rows

    float p[NPW];
#pragma unroll
    for (int r = 0; r < NPW; ++r) p[r] = 0.f;
#pragma unroll
    for (int kq = 0; kq < 4; ++kq) {
        float a0 = W2reg[4 * kq + 0], a1 = W2reg[4 * kq + 1];
        float a2 = W2reg[4 * kq + 2], a3 = W2reg[4 * kq + 3];
#pragma unroll
        for (int r = 0; r < NPW; ++r) {
            float4 z = ((const float4*)(tb8[wv][r] + sub * 16))[kq];
            p[r] = fmaf(z.x, a0, fmaf(z.y, a1, fmaf(z.z, a2, fmaf(z.w, a3, p[r]))));
        }
    }
#pragma unroll
    for (int r = 0; r < NPW; ++r) {
        p[r] += __shfl_xor(p[r], 16);
        p[r] += __shfl_xor(p[r], 32);
        if (lane < 16) out[(size_t)(base + r) * DOUT + m] = p[r] + b2v;
    }
}

// ---------------------------------------------------------------------------
extern "C" void kernel_launch(void* const* d_in, const int* in_sizes, int n_in,
                              void* d_out, int out_size, void* d_ws, size_t ws_size,
                              hipStream_t stream) {
    const float* x   = (const float*)d_in[0];
    const int*   ei  = (const int*)d_in[1];
    const float* W1  = (const float*)d_in[2];
    const float* b1  = (const float*)d_in[3];
    const float* W2  = (const float*)d_in[4];
    const float* b2  = (const float*)d_in[5];
    const float* W3  = (const float*)d_in[6];
    const float* b3  = (const float*)d_in[7];
    const float* Wf1 = (const float*)d_in[8];
    const float* bf1 = (const float*)d_in[9];
    const float* Wf2 = (const float*)d_in[10];
    const float* bf2 = (const float*)d_in[11];
    float* out = (float*)d_out;

    char* ws = (char*)d_ws;
    auto al = [](size_t v) { return (v + 255) & ~(size_t)255; };
    size_t off = 0;
    int* cnt  = (int*)(ws + off);              off = al(off + (size_t)NN * 4);
    int* gcur = (int*)(ws + off);              off = al(off + (size_t)NB * 4);
    int* csr  = (int*)(ws + off);              off = al(off + (size_t)NN * CAP * 4);
    unsigned short* A = (unsigned short*)(ws + off); off = al(off + (size_t)(NN + 1) * DD * 2);
    unsigned short* B = (unsigned short*)(ws + off); off = al(off + (size_t)(NN + 1) * DD * 2);
    float* F  = (float*)(ws + off);            off = al(off + (size_t)NN * DD * 4);

    // bed (16.06 MB) aliases F (25.6 MB): consumed by k_csr, then F is
    // overwritten by layer 3's fp32 output. A/B hold bf16 rows (12.8 MB),
    // sentinel rows at index NN.
    int2* bed = (int2*)F;

    hipMemsetAsync(gcur, 0, (size_t)NB * 4, stream);
    k_scatter2<<<NBL, 256, 0, stream>>>(ei, gcur, bed, (unsigned*)A, (unsigned*)B);
    // CSR (self + edges + sentinel pads, LDS atomics) + fused ts0 -> A
    k_csr<<<NB, 1024, 0, stream>>>(bed, gcur, x, cnt, csr, (unsigned*)A);

    int gf = NN / (4 * NPW);                       // 3125 blocks, exact cover

    // layer 1: ts1 = bf16(relu(dinv*(agg(ts0)@W1)+b1)*dinv) -> B
    k_layer<1><<<gf, 256, 0, stream>>>(A, csr, cnt, b1, W1, B);
    // layer 2: ts2 -> A
    k_layer<1><<<gf, 256, 0, stream>>>(B, csr, cnt, b2, W2, A);
    // layer 3: t3 fp32 (UNSCALED, feeds FFN at full precision) -> F
    k_layer<0><<<gf, 256, 0, stream>>>(A, csr, cnt, b3, W3, F);
    // FFN: out = relu(t3@Wf1+bf1)@Wf2 + bf2
    k_ffn<<<gf, 256, 0, stream>>>(F, Wf1, bf1, Wf2, bf2, out);
}